// Round 1
// baseline (219.797 us; speedup 1.0000x reference)
//
#include <hip/hip_runtime.h>
#include <cstdint>

// ---- problem constants ----
#define B_ROWS 8192
#define XSTR   406      // x row stride (ints)
#define RPB    4        // rows per block
#define NTH    256
#define GAMMA_C 12.0f
#define SCALE_ANG 30.994217f   // PI / sqrt(6/584)  (= PI / EMB_RNG_R)

__device__ __forceinline__ float bfLo(uint32_t u) { return __uint_as_float(u << 16); }
__device__ __forceinline__ float bfHi(uint32_t u) { return __uint_as_float(u & 0xffff0000u); }

__device__ __forceinline__ unsigned short f2bf(float x) {
  uint32_t u = __float_as_uint(x);
  u += 0x7fffu + ((u >> 16) & 1u);   // RNE
  return (unsigned short)(u >> 16);
}

// table[t][j] : j<128 -> cos(t * f_j), j>=128 -> sin(t * f_{j-128}),  f_j = 10000^(-j/128)
__global__ void kge_table(unsigned short* __restrict__ tab) {
  int t = blockIdx.x;       // 0..999
  int j = threadIdx.x;      // 0..127
  double f = pow(10000.0, -(double)j / 128.0);
  double ang = (double)t * f;
  tab[t * 256 + j]       = f2bf((float)cos(ang));
  tab[t * 256 + 128 + j] = f2bf((float)sin(ang));
}

// matvec inner: out[half][j] = sum_k sigma(k) * A[er][k ^ (half*256)] * w_e[k][j]
#define MV_CHUNK(AR, AI)                                                      \
  {                                                                           \
    const float* a0p = &A[er_mv][kc];                                         \
    const float* a1p = &A[er_mv][kc ^ 256];                                   \
    _Pragma("unroll")                                                         \
    for (int kk = 0; kk < 16; kk += 4) {                                      \
      float4 a0 = *(const float4*)(a0p + kk);                                 \
      float4 a1 = *(const float4*)(a1p + kk);                                 \
      _Pragma("unroll")                                                       \
      for (int q = 0; q < 4; ++q) {                                           \
        float av = (q == 0) ? a0.x : (q == 1) ? a0.y : (q == 2) ? a0.z : a0.w;\
        float bv = (q == 0) ? a1.x : (q == 1) ? a1.y : (q == 2) ? a1.z : a1.w;\
        float4 w = *(const float4*)&Wc[kk + q][j0];                           \
        AR.x = fmaf(av, w.x, AR.x); AR.y = fmaf(av, w.y, AR.y);               \
        AR.z = fmaf(av, w.z, AR.z); AR.w = fmaf(av, w.w, AR.w);               \
        AI.x = fmaf(bv, w.x, AI.x); AI.y = fmaf(bv, w.y, AI.y);               \
        AI.z = fmaf(bv, w.z, AI.z); AI.w = fmaf(bv, w.w, AI.w);               \
      }                                                                       \
    }                                                                         \
  }

__global__ __launch_bounds__(NTH) void kge_main(
    const int* __restrict__ x,
    const float* __restrict__ e_emb, const float* __restrict__ r_emb,
    const float* __restrict__ d_frq, const float* __restrict__ d_phi, const float* __restrict__ d_amp,
    const float* __restrict__ m_frq, const float* __restrict__ m_phi, const float* __restrict__ m_amp,
    const float* __restrict__ w_e, const float* __restrict__ w_rp,
    const unsigned short* __restrict__ tab,
    float* __restrict__ out) {
  // er = r*2 + ent  (ent 0 = subject, 1 = object)
  __shared__ __align__(16) float A[2 * RPB][512];    // gathered e_emb rows  (16 KB)
  __shared__ __align__(16) float st[2 * RPB][256];   // t_emb results        (8 KB)
  __shared__ __align__(16) float p[2 * RPB][256];    // matvec out, then rel (8 KB)
  __shared__ __align__(16) float Wc[16][128];        // w_e chunk            (8 KB)
  __shared__ float wrp[RPB][200];                    // w_rp rows            (3.2 KB)
  __shared__ unsigned short cs[RPB][400];            // c values             (3.2 KB)
  __shared__ int meta[RPB][6];

  const int tid = threadIdx.x;
  const int base_row = blockIdx.x * RPB;

  if (tid < RPB * 6) {
    int r = tid / 6, f = tid % 6;
    meta[r][f] = x[(size_t)(base_row + r) * XSTR + f];
  }
  __syncthreads();

  // ---- gather e_emb rows (float4, coalesced) ----
  for (int i = tid; i < 2 * RPB * 128; i += NTH) {
    int er = i >> 7, k4 = i & 127;
    int e = (er & 1) ? meta[er >> 1][2] : meta[er >> 1][0];
    ((float4*)A)[i] = ((const float4*)e_emb)[(size_t)e * 128 + k4];
  }
  // ---- c values ----
  for (int i = tid; i < RPB * 400; i += NTH) {
    int r = i / 400, n = i - r * 400;
    cs[r][n] = (unsigned short)x[(size_t)(base_row + r) * XSTR + 6 + n];
  }
  // ---- w_rp rows ----
  for (int i = tid; i < RPB * 200; i += NTH) {
    int r = i / 200, n = i - r * 200;
    wrp[r][n] = w_rp[(size_t)meta[r][1] * 200 + n];
  }
  // ---- Phase 1: t_emb ----
  for (int it = tid; it < 2 * RPB * 256; it += NTH) {
    int j = it & 255, er = it >> 8, r = er >> 1;
    int e = (er & 1) ? meta[r][2] : meta[r][0];
    float dv = (float)meta[r][3], mv = (float)meta[r][4];
    size_t b256 = (size_t)e * 256 + j, b128 = (size_t)e * 128 + (j & 127);
    float argd = fmaf(dv, d_frq[b256], d_phi[b256]);
    float argm = fmaf(mv, m_frq[b256], m_phi[b256]);
    float vd = (j < 128) ? d_amp[b128] * cosf(argd) : d_amp[b128] * sinf(argd);
    float vm = (j < 128) ? m_amp[b128] * cosf(argm) : m_amp[b128] * sinf(argm);
    st[er][j] = vd + vm;
  }

  // ---- Phase 2: e_p_emb matvec ----
  const int er_mv = tid >> 5;          // 0..7
  const int j0 = (tid & 31) * 4;       // output column group
  float4 pRe = {0, 0, 0, 0}, pIm = {0, 0, 0, 0};
  float4 nRe = {0, 0, 0, 0}, nIm = {0, 0, 0, 0};
  for (int kc = 0; kc < 512; kc += 16) {
    __syncthreads();                               // also closes phase-0/1 writes on first iter
    for (int i = tid; i < 512; i += NTH)           // stage 16x128 chunk of w_e
      ((float4*)Wc)[i] = ((const float4*)w_e)[kc * 32 + i];
    __syncthreads();
    if (kc < 256) MV_CHUNK(pRe, pIm) else MV_CHUNK(nRe, nIm);
  }
  p[er_mv][j0 + 0] = pRe.x - nRe.x; p[er_mv][j0 + 1] = pRe.y - nRe.y;
  p[er_mv][j0 + 2] = pRe.z - nRe.z; p[er_mv][j0 + 3] = pRe.w - nRe.w;
  p[er_mv][128 + j0 + 0] = pIm.x - nIm.x; p[er_mv][128 + j0 + 1] = pIm.y - nIm.y;
  p[er_mv][128 + j0 + 2] = pIm.z - nIm.z; p[er_mv][128 + j0 + 3] = pIm.w - nIm.w;
  __syncthreads();

  // ---- Phase 3: e_r_emb, accumulate into p ----
  const int wv = tid >> 6, l = tid & 63;
  for (int pass = 0; pass < 2; ++pass) {
    int er = wv + 4 * pass;            // 0..7
    int r = er >> 1, ent = er & 1;
    float acc0 = 0.f, acc1 = 0.f, acc2 = 0.f, acc3 = 0.f;
    if (tab) {
      const uint32_t* tu = (const uint32_t*)tab;
      #pragma unroll 4
      for (int n = 0; n < 200; ++n) {
        int c = cs[r][ent * 200 + n];
        float w = wrp[r][n];
        uint32_t cw = tu[c * 128 + l];       // cos pair (2j, 2j+1)
        uint32_t sw = tu[c * 128 + 64 + l];  // sin pair
        acc0 = fmaf(w, bfLo(cw), acc0); acc1 = fmaf(w, bfHi(cw), acc1);
        acc2 = fmaf(w, bfLo(sw), acc2); acc3 = fmaf(w, bfHi(sw), acc3);
      }
    } else {
      float f0 = (float)pow(10000.0, -(double)(2 * l) / 128.0);
      float f1 = (float)pow(10000.0, -(double)(2 * l + 1) / 128.0);
      for (int n = 0; n < 200; ++n) {
        float c = (float)cs[r][ent * 200 + n];
        float w = wrp[r][n];
        float s0, c0, s1, c1;
        sincosf(c * f0, &s0, &c0);
        sincosf(c * f1, &s1, &c1);
        acc0 = fmaf(w, c0, acc0); acc1 = fmaf(w, c1, acc1);
        acc2 = fmaf(w, s0, acc2); acc3 = fmaf(w, s1, acc3);
      }
    }
    p[er][2 * l]       += acc0;
    p[er][2 * l + 1]   += acc1;
    p[er][128 + 2 * l] += acc2;
    p[er][129 + 2 * l] += acc3;
  }
  __syncthreads();

  // ---- Phase 4: scores (one wave per row) ----
  {
    int r = wv;
    int rid = meta[r][1];
    float sabs = 0.f;
    for (int u = l; u < 384; u += 64) {
      float ang = r_emb[(size_t)rid * 384 + u] * SCALE_ANG;
      float sr, cr;
      sincosf(ang, &sr, &cr);
      float res, ims, reo, imo;
      if (u < 256) {
        res = A[2 * r][u];     ims = A[2 * r][256 + u];
        reo = A[2 * r + 1][u]; imo = A[2 * r + 1][256 + u];
      } else {
        int uu = u - 256;
        res = st[2 * r][uu];     ims = st[2 * r][128 + uu];
        reo = st[2 * r + 1][uu]; imo = st[2 * r + 1][128 + uu];
      }
      float rsc = res * cr - ims * sr - reo;
      float isc = res * sr + ims * cr - imo;
      sabs += sqrtf(rsc * rsc + isc * isc);
    }
    float srel = 0.f;
    for (int u = l; u < 128; u += 64) {
      float dre = p[2 * r][u] - p[2 * r + 1][u];
      float dim = p[2 * r][128 + u] - p[2 * r + 1][128 + u];
      srel += sqrtf(dre * dre + dim * dim);
    }
    float tot = sabs + srel;
    #pragma unroll
    for (int off = 32; off > 0; off >>= 1) tot += __shfl_down(tot, off);
    if (l == 0) out[base_row + r] = GAMMA_C - tot;
  }
}

extern "C" void kernel_launch(void* const* d_in, const int* in_sizes, int n_in,
                              void* d_out, int out_size, void* d_ws, size_t ws_size,
                              hipStream_t stream) {
  (void)in_sizes; (void)n_in; (void)out_size;
  const int*   x     = (const int*)d_in[0];
  const float* e_emb = (const float*)d_in[1];
  const float* r_emb = (const float*)d_in[2];
  const float* d_frq = (const float*)d_in[3];
  const float* d_phi = (const float*)d_in[4];
  const float* d_amp = (const float*)d_in[5];
  const float* m_frq = (const float*)d_in[6];
  const float* m_phi = (const float*)d_in[7];
  const float* m_amp = (const float*)d_in[8];
  const float* w_e   = (const float*)d_in[9];
  const float* w_rp  = (const float*)d_in[10];
  float* out = (float*)d_out;

  unsigned short* tab = nullptr;
  if (ws_size >= (size_t)(1000 * 256 * 2)) {
    tab = (unsigned short*)d_ws;
    kge_table<<<dim3(1000), dim3(128), 0, stream>>>(tab);
  }
  kge_main<<<dim3(B_ROWS / RPB), dim3(NTH), 0, stream>>>(
      x, e_emb, r_emb, d_frq, d_phi, d_amp, m_frq, m_phi, m_amp, w_e, w_rp, tab, out);
}

// Round 2
// 166.256 us; speedup vs baseline: 1.3220x; 1.3220x over previous
//
#include <hip/hip_runtime.h>
#include <cstdint>

// ---- problem constants ----
#define B_ROWS 8192
#define XSTR   406      // x row stride (ints)
#define GAMMA_C 12.0f
#define SCALE_ANG 30.994217f   // PI / sqrt(6/584)

// ---- new-path config ----
#define NTH    512
#define RPB    8
#define ERB    (2*RPB)         // 16 entity rows / block
#define APAD   520             // A row stride in bf16 elems (pad vs 512 for LDS banks)
#define TAB_BYTES   (1000*256*2)   // 512000
#define WCAT_BYTES  (512*256*2)    // 262144
#define WS_NEED     ((size_t)(TAB_BYTES + WCAT_BYTES))

typedef __attribute__((ext_vector_type(8))) short short8v;
typedef __attribute__((ext_vector_type(4))) float float4v;

__device__ __forceinline__ float bfLo(uint32_t u) { return __uint_as_float(u << 16); }
__device__ __forceinline__ float bfHi(uint32_t u) { return __uint_as_float(u & 0xffff0000u); }
__device__ __forceinline__ float bf1(unsigned short u) { return __uint_as_float((uint32_t)u << 16); }

__device__ __forceinline__ unsigned short f2bf(float x) {
  uint32_t u = __float_as_uint(x);
  u += 0x7fffu + ((u >> 16) & 1u);   // RNE
  return (unsigned short)(u >> 16);
}

// ---------------------------------------------------------------------------
// Prep 1: trig table, quad-interleaved so phase 3 does ONE dwordx2 per n:
//   tab[t][4q+0,1] = cos(t*f_{2q}), cos(t*f_{2q+1})
//   tab[t][4q+2,3] = sin(t*f_{2q}), sin(t*f_{2q+1})
__global__ void kge_table(unsigned short* __restrict__ tab) {
  int t = blockIdx.x;       // 0..999
  int j = threadIdx.x;      // 0..127 (freq index)
  double f = pow(10000.0, -(double)j / 128.0);
  double ang = (double)t * f;
  int q = j >> 1, lo = j & 1;
  tab[t * 256 + 4 * q + lo]     = f2bf((float)cos(ang));
  tab[t * 256 + 4 * q + 2 + lo] = f2bf((float)sin(ang));
}

// ---------------------------------------------------------------------------
// Prep 2: sign-folded weights Wcat (512x256) in MFMA-B-fragment order (bf16).
// Logical: Wcat[k][c] = (c<128) ?  sigma(k)*w_e[k][c]
//                               : -sigma(k)*w_e[k^256][c-128],  sigma(k)=k<256?+1:-1
// Swizzle: frag (kk 0..15, nt 0..15), lane l, elem j <-> k=kk*32+(l>>4)*8+j, c=nt*16+(l&15)
__global__ void kge_wcat(const float* __restrict__ w_e, unsigned short* __restrict__ wcat) {
  int bid = blockIdx.x;            // kk*16 + nt
  int kk = bid >> 4, nt = bid & 15;
  int l = threadIdx.x;             // 0..63
  __align__(16) unsigned short v[8];
  int c = nt * 16 + (l & 15);
  #pragma unroll
  for (int j = 0; j < 8; ++j) {
    int k = kk * 32 + ((l >> 4) << 3) + j;
    float s = (k < 256) ? 1.f : -1.f;
    float val = (c < 128) ? s * w_e[k * 128 + c]
                          : -s * w_e[(k ^ 256) * 128 + (c - 128)];
    v[j] = f2bf(val);
  }
  ((uint4*)wcat)[bid * 64 + l] = *(const uint4*)v;
}

// ---------------------------------------------------------------------------
// Main fused kernel (8 rows/block, 512 threads, MFMA phase 2)
__global__ __launch_bounds__(NTH, 4) void kge_main2(
    const int* __restrict__ x,
    const float* __restrict__ e_emb, const float* __restrict__ r_emb,
    const float* __restrict__ d_frq, const float* __restrict__ d_phi, const float* __restrict__ d_amp,
    const float* __restrict__ m_frq, const float* __restrict__ m_phi, const float* __restrict__ m_amp,
    const float* __restrict__ w_rp,
    const unsigned short* __restrict__ tab, const unsigned short* __restrict__ wcat,
    float* __restrict__ out) {
  __shared__ __align__(16) unsigned short A[ERB][APAD];    // e_emb rows, bf16 (16.6 KB)
  __shared__ __align__(16) unsigned short stb[ERB][256];   // t_emb, bf16     (8 KB)
  __shared__ __align__(16) float p[ERB][256];              // rel embedding   (16 KB)
  __shared__ unsigned short cs[RPB][400];                  // c values        (6.4 KB)
  __shared__ unsigned short wrb[RPB][200];                 // w_rp, bf16      (3.2 KB)
  __shared__ int meta[RPB][6];

  const int tid = threadIdx.x;
  const int base_row = blockIdx.x * RPB;

  if (tid < RPB * 6) {
    int r = tid / 6, f = tid % 6;
    meta[r][f] = x[(size_t)(base_row + r) * XSTR + f];
  }
  __syncthreads();

  // ---- gather e_emb rows -> A (bf16, float4 reads) ----
  for (int i = tid; i < ERB * 128; i += NTH) {
    int er = i >> 7, k4 = i & 127;
    int e = (er & 1) ? meta[er >> 1][2] : meta[er >> 1][0];
    float4 v = ((const float4*)e_emb)[(size_t)e * 128 + k4];
    unsigned short* dst = &A[er][k4 * 4];
    dst[0] = f2bf(v.x); dst[1] = f2bf(v.y); dst[2] = f2bf(v.z); dst[3] = f2bf(v.w);
  }
  // ---- c values ----
  for (int i = tid; i < RPB * 400; i += NTH) {
    int r = i / 400, n = i - r * 400;
    cs[r][n] = (unsigned short)x[(size_t)(base_row + r) * XSTR + 6 + n];
  }
  // ---- w_rp rows (bf16) ----
  for (int i = tid; i < RPB * 200; i += NTH) {
    int r = i / 200, n = i - r * 200;
    wrb[r][n] = f2bf(w_rp[(size_t)meta[r][1] * 200 + n]);
  }
  // ---- Phase 1: t_emb -> stb ----
  for (int it = tid; it < ERB * 256; it += NTH) {
    int j = it & 255, er = it >> 8, r = er >> 1;
    int e = (er & 1) ? meta[r][2] : meta[r][0];
    float dv = (float)meta[r][3], mv = (float)meta[r][4];
    size_t b256 = (size_t)e * 256 + j, b128 = (size_t)e * 128 + (j & 127);
    float argd = fmaf(dv, d_frq[b256], d_phi[b256]);
    float argm = fmaf(mv, m_frq[b256], m_phi[b256]);
    float vd = (j < 128) ? d_amp[b128] * cosf(argd) : d_amp[b128] * sinf(argd);
    float vm = (j < 128) ? m_amp[b128] * cosf(argm) : m_amp[b128] * sinf(argm);
    stb[er][j] = f2bf(vd + vm);
  }
  __syncthreads();

  const int w = tid >> 6, l = tid & 63;

  // ---- Phase 2: p = A @ Wcat via MFMA (wave w owns col tiles 2w, 2w+1) ----
  {
    float4v acc0 = {0, 0, 0, 0}, acc1 = {0, 0, 0, 0};
    const int nt0 = 2 * w, nt1 = 2 * w + 1;
    const short8v* bp = (const short8v*)wcat;
    const unsigned short* arow = &A[l & 15][(l >> 4) << 3];
    #pragma unroll 8
    for (int kk = 0; kk < 16; ++kk) {
      short8v a  = *(const short8v*)(arow + kk * 32);
      short8v b0 = bp[(kk * 16 + nt0) * 64 + l];
      short8v b1 = bp[(kk * 16 + nt1) * 64 + l];
      acc0 = __builtin_amdgcn_mfma_f32_16x16x32_bf16(a, b0, acc0, 0, 0, 0);
      acc1 = __builtin_amdgcn_mfma_f32_16x16x32_bf16(a, b1, acc1, 0, 0, 0);
    }
    int col = l & 15, rbase = (l >> 4) * 4;
    #pragma unroll
    for (int q = 0; q < 4; ++q) {
      p[rbase + q][nt0 * 16 + col] = acc0[q];
      p[rbase + q][nt1 * 16 + col] = acc1[q];
    }
  }
  __syncthreads();

  // ---- Phase 3: e_r_emb table gather-MAC, accumulate into p ----
  {
    const uint2* tl = ((const uint2*)tab) + l;   // lane's quad within each row
    #pragma unroll
    for (int pass = 0; pass < 2; ++pass) {
      int er = w + 8 * pass;
      int r = er >> 1, ent = er & 1;
      float a0 = 0.f, a1 = 0.f, a2 = 0.f, a3 = 0.f;
      const unsigned short* cp = &cs[r][ent * 200];
      const unsigned short* wp = &wrb[r][0];
      #pragma unroll 4
      for (int n = 0; n < 200; ++n) {
        int c = cp[n];
        float wv = bf1(wp[n]);
        uint2 q = tl[c * 64];
        a0 = fmaf(wv, bfLo(q.x), a0);
        a1 = fmaf(wv, bfHi(q.x), a1);
        a2 = fmaf(wv, bfLo(q.y), a2);
        a3 = fmaf(wv, bfHi(q.y), a3);
      }
      p[er][2 * l]       += a0;
      p[er][2 * l + 1]   += a1;
      p[er][128 + 2 * l] += a2;
      p[er][129 + 2 * l] += a3;
    }
  }
  __syncthreads();

  // ---- Phase 4: scores (wave w -> row w) ----
  {
    int r = w;
    int rid = meta[r][1];
    float sabs = 0.f;
    #pragma unroll
    for (int u0 = 0; u0 < 384; u0 += 64) {
      int u = u0 + l;
      float ang = r_emb[(size_t)rid * 384 + u] * SCALE_ANG;
      float sr, cr;
      sincosf(ang, &sr, &cr);
      float res, ims, reo, imo;
      if (u < 256) {
        res = bf1(A[2 * r][u]);       ims = bf1(A[2 * r][256 + u]);
        reo = bf1(A[2 * r + 1][u]);   imo = bf1(A[2 * r + 1][256 + u]);
      } else {
        int uu = u - 256;
        res = bf1(stb[2 * r][uu]);     ims = bf1(stb[2 * r][128 + uu]);
        reo = bf1(stb[2 * r + 1][uu]); imo = bf1(stb[2 * r + 1][128 + uu]);
      }
      float rsc = res * cr - ims * sr - reo;
      float isc = res * sr + ims * cr - imo;
      sabs += sqrtf(rsc * rsc + isc * isc);
    }
    float srel = 0.f;
    #pragma unroll
    for (int u0 = 0; u0 < 128; u0 += 64) {
      int u = u0 + l;
      float dre = p[2 * r][u] - p[2 * r + 1][u];
      float dim = p[2 * r][128 + u] - p[2 * r + 1][128 + u];
      srel += sqrtf(dre * dre + dim * dim);
    }
    float tot = sabs + srel;
    #pragma unroll
    for (int off = 32; off > 0; off >>= 1) tot += __shfl_down(tot, off);
    if (l == 0) out[base_row + r] = GAMMA_C - tot;
  }
}

// ===========================================================================
// Fallback (round-1 kernel, inline-sincos path) in case ws_size is too small.
#define FNTH 256
#define FRPB 4

#define MV_CHUNK(AR, AI)                                                      \
  {                                                                           \
    const float* a0p = &Af[er_mv][kc];                                        \
    const float* a1p = &Af[er_mv][kc ^ 256];                                  \
    _Pragma("unroll")                                                         \
    for (int kk = 0; kk < 16; kk += 4) {                                      \
      float4 a0 = *(const float4*)(a0p + kk);                                 \
      float4 a1 = *(const float4*)(a1p + kk);                                 \
      _Pragma("unroll")                                                       \
      for (int q = 0; q < 4; ++q) {                                           \
        float av = (q == 0) ? a0.x : (q == 1) ? a0.y : (q == 2) ? a0.z : a0.w;\
        float bv = (q == 0) ? a1.x : (q == 1) ? a1.y : (q == 2) ? a1.z : a1.w;\
        float4 wq = *(const float4*)&Wc[kk + q][j0];                          \
        AR.x = fmaf(av, wq.x, AR.x); AR.y = fmaf(av, wq.y, AR.y);             \
        AR.z = fmaf(av, wq.z, AR.z); AR.w = fmaf(av, wq.w, AR.w);             \
        AI.x = fmaf(bv, wq.x, AI.x); AI.y = fmaf(bv, wq.y, AI.y);             \
        AI.z = fmaf(bv, wq.z, AI.z); AI.w = fmaf(bv, wq.w, AI.w);             \
      }                                                                       \
    }                                                                         \
  }

__global__ __launch_bounds__(FNTH) void kge_main_fb(
    const int* __restrict__ x,
    const float* __restrict__ e_emb, const float* __restrict__ r_emb,
    const float* __restrict__ d_frq, const float* __restrict__ d_phi, const float* __restrict__ d_amp,
    const float* __restrict__ m_frq, const float* __restrict__ m_phi, const float* __restrict__ m_amp,
    const float* __restrict__ w_e, const float* __restrict__ w_rp,
    float* __restrict__ out) {
  __shared__ __align__(16) float Af[2 * FRPB][512];
  __shared__ __align__(16) float st[2 * FRPB][256];
  __shared__ __align__(16) float p[2 * FRPB][256];
  __shared__ __align__(16) float Wc[16][128];
  __shared__ float wrp[FRPB][200];
  __shared__ unsigned short cs[FRPB][400];
  __shared__ int meta[FRPB][6];

  const int tid = threadIdx.x;
  const int base_row = blockIdx.x * FRPB;

  if (tid < FRPB * 6) {
    int r = tid / 6, f = tid % 6;
    meta[r][f] = x[(size_t)(base_row + r) * XSTR + f];
  }
  __syncthreads();
  for (int i = tid; i < 2 * FRPB * 128; i += FNTH) {
    int er = i >> 7, k4 = i & 127;
    int e = (er & 1) ? meta[er >> 1][2] : meta[er >> 1][0];
    ((float4*)Af)[i] = ((const float4*)e_emb)[(size_t)e * 128 + k4];
  }
  for (int i = tid; i < FRPB * 400; i += FNTH) {
    int r = i / 400, n = i - r * 400;
    cs[r][n] = (unsigned short)x[(size_t)(base_row + r) * XSTR + 6 + n];
  }
  for (int i = tid; i < FRPB * 200; i += FNTH) {
    int r = i / 200, n = i - r * 200;
    wrp[r][n] = w_rp[(size_t)meta[r][1] * 200 + n];
  }
  for (int it = tid; it < 2 * FRPB * 256; it += FNTH) {
    int j = it & 255, er = it >> 8, r = er >> 1;
    int e = (er & 1) ? meta[r][2] : meta[r][0];
    float dv = (float)meta[r][3], mv = (float)meta[r][4];
    size_t b256 = (size_t)e * 256 + j, b128 = (size_t)e * 128 + (j & 127);
    float argd = fmaf(dv, d_frq[b256], d_phi[b256]);
    float argm = fmaf(mv, m_frq[b256], m_phi[b256]);
    float vd = (j < 128) ? d_amp[b128] * cosf(argd) : d_amp[b128] * sinf(argd);
    float vm = (j < 128) ? m_amp[b128] * cosf(argm) : m_amp[b128] * sinf(argm);
    st[er][j] = vd + vm;
  }

  const int er_mv = tid >> 5;
  const int j0 = (tid & 31) * 4;
  float4 pRe = {0, 0, 0, 0}, pIm = {0, 0, 0, 0};
  float4 nRe = {0, 0, 0, 0}, nIm = {0, 0, 0, 0};
  for (int kc = 0; kc < 512; kc += 16) {
    __syncthreads();
    for (int i = tid; i < 512; i += FNTH)
      ((float4*)Wc)[i] = ((const float4*)w_e)[kc * 32 + i];
    __syncthreads();
    if (kc < 256) MV_CHUNK(pRe, pIm) else MV_CHUNK(nRe, nIm);
  }
  p[er_mv][j0 + 0] = pRe.x - nRe.x; p[er_mv][j0 + 1] = pRe.y - nRe.y;
  p[er_mv][j0 + 2] = pRe.z - nRe.z; p[er_mv][j0 + 3] = pRe.w - nRe.w;
  p[er_mv][128 + j0 + 0] = pIm.x - nIm.x; p[er_mv][128 + j0 + 1] = pIm.y - nIm.y;
  p[er_mv][128 + j0 + 2] = pIm.z - nIm.z; p[er_mv][128 + j0 + 3] = pIm.w - nIm.w;
  __syncthreads();

  const int wv = tid >> 6, l = tid & 63;
  for (int pass = 0; pass < 2; ++pass) {
    int er = wv + 4 * pass;
    int r = er >> 1, ent = er & 1;
    float acc0 = 0.f, acc1 = 0.f, acc2 = 0.f, acc3 = 0.f;
    float f0 = (float)pow(10000.0, -(double)(2 * l) / 128.0);
    float f1 = (float)pow(10000.0, -(double)(2 * l + 1) / 128.0);
    for (int n = 0; n < 200; ++n) {
      float c = (float)cs[r][ent * 200 + n];
      float wt = wrp[r][n];
      float s0, c0, s1, c1;
      sincosf(c * f0, &s0, &c0);
      sincosf(c * f1, &s1, &c1);
      acc0 = fmaf(wt, c0, acc0); acc1 = fmaf(wt, c1, acc1);
      acc2 = fmaf(wt, s0, acc2); acc3 = fmaf(wt, s1, acc3);
    }
    p[er][2 * l]       += acc0;
    p[er][2 * l + 1]   += acc1;
    p[er][128 + 2 * l] += acc2;
    p[er][129 + 2 * l] += acc3;
  }
  __syncthreads();

  {
    int r = wv;
    int rid = meta[r][1];
    float sabs = 0.f;
    for (int u = l; u < 384; u += 64) {
      float ang = r_emb[(size_t)rid * 384 + u] * SCALE_ANG;
      float sr, cr;
      sincosf(ang, &sr, &cr);
      float res, ims, reo, imo;
      if (u < 256) {
        res = Af[2 * r][u];     ims = Af[2 * r][256 + u];
        reo = Af[2 * r + 1][u]; imo = Af[2 * r + 1][256 + u];
      } else {
        int uu = u - 256;
        res = st[2 * r][uu];     ims = st[2 * r][128 + uu];
        reo = st[2 * r + 1][uu]; imo = st[2 * r + 1][128 + uu];
      }
      float rsc = res * cr - ims * sr - reo;
      float isc = res * sr + ims * cr - imo;
      sabs += sqrtf(rsc * rsc + isc * isc);
    }
    float srel = 0.f;
    for (int u = l; u < 128; u += 64) {
      float dre = p[2 * r][u] - p[2 * r + 1][u];
      float dim = p[2 * r][128 + u] - p[2 * r + 1][128 + u];
      srel += sqrtf(dre * dre + dim * dim);
    }
    float tot = sabs + srel;
    #pragma unroll
    for (int off = 32; off > 0; off >>= 1) tot += __shfl_down(tot, off);
    if (l == 0) out[base_row + r] = GAMMA_C - tot;
  }
}

// ===========================================================================
extern "C" void kernel_launch(void* const* d_in, const int* in_sizes, int n_in,
                              void* d_out, int out_size, void* d_ws, size_t ws_size,
                              hipStream_t stream) {
  (void)in_sizes; (void)n_in; (void)out_size;
  const int*   x     = (const int*)d_in[0];
  const float* e_emb = (const float*)d_in[1];
  const float* r_emb = (const float*)d_in[2];
  const float* d_frq = (const float*)d_in[3];
  const float* d_phi = (const float*)d_in[4];
  const float* d_amp = (const float*)d_in[5];
  const float* m_frq = (const float*)d_in[6];
  const float* m_phi = (const float*)d_in[7];
  const float* m_amp = (const float*)d_in[8];
  const float* w_e   = (const float*)d_in[9];
  const float* w_rp  = (const float*)d_in[10];
  float* out = (float*)d_out;

  if (ws_size >= WS_NEED) {
    unsigned short* tab  = (unsigned short*)d_ws;
    unsigned short* wcat = (unsigned short*)((char*)d_ws + TAB_BYTES);
    kge_table<<<dim3(1000), dim3(128), 0, stream>>>(tab);
    kge_wcat<<<dim3(256), dim3(64), 0, stream>>>(w_e, wcat);
    kge_main2<<<dim3(B_ROWS / RPB), dim3(NTH), 0, stream>>>(
        x, e_emb, r_emb, d_frq, d_phi, d_amp, m_frq, m_phi, m_amp, w_rp,
        tab, wcat, out);
  } else {
    kge_main_fb<<<dim3(B_ROWS / FRPB), dim3(FNTH), 0, stream>>>(
        x, e_emb, r_emb, d_frq, d_phi, d_amp, m_frq, m_phi, m_amp, w_e, w_rp, out);
  }
}

// Round 3
// 144.680 us; speedup vs baseline: 1.5192x; 1.1491x over previous
//
#include <hip/hip_runtime.h>
#include <cstdint>

// ---- problem constants ----
#define B_ROWS 8192
#define XSTR   406      // x row stride (ints)
#define GAMMA_C 12.0f
#define SCALE_ANG 30.994217f   // PI / sqrt(6/584)

// ---- config ----
#define NTH    512
#define RPB    8
#define ERB    (2*RPB)         // 16 entity rows / block
#define APAD   520             // A row stride in bf16 elems (16B-aligned, odd 16B units)
#define TAB_BYTES   (1000*256*2)   // 512000
#define WCAT_BYTES  (512*256*2)    // 262144
#define WS_NEED     ((size_t)(TAB_BYTES + WCAT_BYTES))

typedef __attribute__((ext_vector_type(8))) short short8v;
typedef __attribute__((ext_vector_type(4))) float float4v;

__device__ __forceinline__ float bfLo(uint32_t u) { return __uint_as_float(u << 16); }
__device__ __forceinline__ float bfHi(uint32_t u) { return __uint_as_float(u & 0xffff0000u); }
__device__ __forceinline__ float bf1(unsigned short u) { return __uint_as_float((uint32_t)u << 16); }

__device__ __forceinline__ uint32_t f2bf_u(float x) {
  uint32_t u = __float_as_uint(x);
  u += 0x7fffu + ((u >> 16) & 1u);   // RNE
  return u >> 16;
}
__device__ __forceinline__ unsigned short f2bf(float x) { return (unsigned short)f2bf_u(x); }

// ---------------------------------------------------------------------------
// Prep 1: trig table, quad-interleaved so phase 3 does ONE dwordx2 per (n,ent):
//   tab[t][4q+0,1] = cos(t*f_{2q}), cos(t*f_{2q+1})
//   tab[t][4q+2,3] = sin(t*f_{2q}), sin(t*f_{2q+1})
__global__ void kge_table(unsigned short* __restrict__ tab) {
  int t = blockIdx.x;       // 0..999
  int j = threadIdx.x;      // 0..127 (freq index)
  double f = pow(10000.0, -(double)j / 128.0);
  double ang = (double)t * f;
  int q = j >> 1, lo = j & 1;
  tab[t * 256 + 4 * q + lo]     = f2bf((float)cos(ang));
  tab[t * 256 + 4 * q + 2 + lo] = f2bf((float)sin(ang));
}

// ---------------------------------------------------------------------------
// Prep 2: sign-folded weights Wcat (512x256) in MFMA-B-fragment order (bf16).
// Logical: Wcat[k][c] = (c<128) ?  sigma(k)*w_e[k][c]
//                               : -sigma(k)*w_e[k^256][c-128],  sigma(k)=k<256?+1:-1
// Swizzle: frag (kk 0..15, nt 0..15), lane l, elem j <-> k=kk*32+(l>>4)*8+j, c=nt*16+(l&15)
__global__ void kge_wcat(const float* __restrict__ w_e, unsigned short* __restrict__ wcat) {
  int bid = blockIdx.x;            // kk*16 + nt
  int kk = bid >> 4, nt = bid & 15;
  int l = threadIdx.x;             // 0..63
  __align__(16) unsigned short v[8];
  int c = nt * 16 + (l & 15);
  #pragma unroll
  for (int j = 0; j < 8; ++j) {
    int k = kk * 32 + ((l >> 4) << 3) + j;
    float s = (k < 256) ? 1.f : -1.f;
    float val = (c < 128) ? s * w_e[k * 128 + c]
                          : -s * w_e[(k ^ 256) * 128 + (c - 128)];
    v[j] = f2bf(val);
  }
  ((uint4*)wcat)[bid * 64 + l] = *(const uint4*)v;
}

// ---------------------------------------------------------------------------
// Main fused kernel
__global__ __launch_bounds__(NTH, 4) void kge_main3(
    const int* __restrict__ x,
    const float* __restrict__ e_emb, const float* __restrict__ r_emb,
    const float* __restrict__ d_frq, const float* __restrict__ d_phi, const float* __restrict__ d_amp,
    const float* __restrict__ m_frq, const float* __restrict__ m_phi, const float* __restrict__ m_amp,
    const float* __restrict__ w_rp,
    const unsigned short* __restrict__ tab, const unsigned short* __restrict__ wcat,
    float* __restrict__ out) {
  __shared__ __align__(16) unsigned short A[ERB][APAD];    // e_emb rows, bf16 (16.6 KB)
  __shared__ __align__(16) unsigned short stb[ERB][256];   // t_emb, bf16      (8 KB)
  __shared__ __align__(16) float p[ERB][256];              // rel embedding    (16 KB)
  __shared__ int meta[RPB][6];

  const int tid = threadIdx.x;
  const int base_row = blockIdx.x * RPB;
  const int w = tid >> 6, l = tid & 63;

  if (tid < RPB * 6) {
    int r = tid / 6, f = tid % 6;
    meta[r][f] = x[(size_t)(base_row + r) * XSTR + f];
  }
  __syncthreads();

  // ---- gather e_emb rows -> A (bf16, packed ds_write_b64) ----
  for (int i = tid; i < ERB * 128; i += NTH) {
    int er = i >> 7, k4 = i & 127;
    int e = (er & 1) ? meta[er >> 1][2] : meta[er >> 1][0];
    float4 v = ((const float4*)e_emb)[(size_t)e * 128 + k4];
    uint2 pk;
    pk.x = f2bf_u(v.x) | (f2bf_u(v.y) << 16);
    pk.y = f2bf_u(v.z) | (f2bf_u(v.w) << 16);
    *(uint2*)&A[er][k4 * 4] = pk;
  }
  // ---- Phase 1: t_emb -> stb ----
  for (int it = tid; it < ERB * 256; it += NTH) {
    int j = it & 255, er = it >> 8, r = er >> 1;
    int e = (er & 1) ? meta[r][2] : meta[r][0];
    float dv = (float)meta[r][3], mv = (float)meta[r][4];
    size_t b256 = (size_t)e * 256 + j, b128 = (size_t)e * 128 + (j & 127);
    float argd = fmaf(dv, d_frq[b256], d_phi[b256]);
    float argm = fmaf(mv, m_frq[b256], m_phi[b256]);
    float vd = (j < 128) ? d_amp[b128] * cosf(argd) : d_amp[b128] * sinf(argd);
    float vm = (j < 128) ? m_amp[b128] * cosf(argm) : m_amp[b128] * sinf(argm);
    stb[er][j] = f2bf(vd + vm);
  }

  // ---- Phase 3 (registers): e_r_emb gather-MAC, both entities of row wu ----
  // c and w_rp reads are wave-uniform -> SGPR s_loads (no LDS pipe, no VGPR addr).
  float s0 = 0, s1 = 0, s2 = 0, s3 = 0, o0 = 0, o1 = 0, o2 = 0, o3 = 0;
  {
    const int wu  = __builtin_amdgcn_readfirstlane(w);
    const int rid = __builtin_amdgcn_readfirstlane(meta[wu][1]);
    const int*   cp = x + (size_t)(base_row + wu) * XSTR + 6;
    const float* wp = w_rp + (size_t)rid * 200;
    const uint2* tl = ((const uint2*)tab) + l;
    #pragma unroll 2
    for (int n = 0; n < 200; ++n) {
      float wv = wp[n];
      int cS = cp[n];
      int cO = cp[200 + n];
      uint2 qs = tl[(size_t)cS * 64];
      uint2 qo = tl[(size_t)cO * 64];
      s0 = fmaf(wv, bfLo(qs.x), s0); s1 = fmaf(wv, bfHi(qs.x), s1);
      s2 = fmaf(wv, bfLo(qs.y), s2); s3 = fmaf(wv, bfHi(qs.y), s3);
      o0 = fmaf(wv, bfLo(qo.x), o0); o1 = fmaf(wv, bfHi(qo.x), o1);
      o2 = fmaf(wv, bfLo(qo.y), o2); o3 = fmaf(wv, bfHi(qo.y), o3);
    }
  }
  __syncthreads();   // A, stb ready

  // ---- Phase 2: p = A @ Wcat via MFMA (wave w owns col tiles 2w, 2w+1) ----
  {
    float4v acc0 = {0, 0, 0, 0}, acc1 = {0, 0, 0, 0};
    const int nt0 = 2 * w, nt1 = 2 * w + 1;
    const short8v* bp = (const short8v*)wcat;
    const unsigned short* arow = &A[l & 15][(l >> 4) << 3];
    #pragma unroll 8
    for (int kk = 0; kk < 16; ++kk) {
      short8v a  = *(const short8v*)(arow + kk * 32);
      short8v b0 = bp[(kk * 16 + nt0) * 64 + l];
      short8v b1 = bp[(kk * 16 + nt1) * 64 + l];
      acc0 = __builtin_amdgcn_mfma_f32_16x16x32_bf16(a, b0, acc0, 0, 0, 0);
      acc1 = __builtin_amdgcn_mfma_f32_16x16x32_bf16(a, b1, acc1, 0, 0, 0);
    }
    int col = l & 15, rbase = (l >> 4) * 4;
    #pragma unroll
    for (int q = 0; q < 4; ++q) {
      p[rbase + q][nt0 * 16 + col] = acc0[q];
      p[rbase + q][nt1 * 16 + col] = acc1[q];
    }
  }
  __syncthreads();

  // ---- merge phase-3 accumulators into p (wave w owns rows 2w, 2w+1) ----
  {
    int es = 2 * w, eo = 2 * w + 1;
    p[es][2 * l] += s0; p[es][2 * l + 1] += s1;
    p[es][128 + 2 * l] += s2; p[es][129 + 2 * l] += s3;
    p[eo][2 * l] += o0; p[eo][2 * l + 1] += o1;
    p[eo][128 + 2 * l] += o2; p[eo][129 + 2 * l] += o3;
  }
  __syncthreads();

  // ---- Phase 4: scores (wave w -> row w) ----
  {
    int r = w;
    int rid = meta[r][1];
    float sabs = 0.f;
    #pragma unroll
    for (int u0 = 0; u0 < 384; u0 += 64) {
      int u = u0 + l;
      float ang = r_emb[(size_t)rid * 384 + u] * SCALE_ANG;
      float sr, cr;
      sincosf(ang, &sr, &cr);
      float res, ims, reo, imo;
      if (u < 256) {
        res = bf1(A[2 * r][u]);       ims = bf1(A[2 * r][256 + u]);
        reo = bf1(A[2 * r + 1][u]);   imo = bf1(A[2 * r + 1][256 + u]);
      } else {
        int uu = u - 256;
        res = bf1(stb[2 * r][uu]);     ims = bf1(stb[2 * r][128 + uu]);
        reo = bf1(stb[2 * r + 1][uu]); imo = bf1(stb[2 * r + 1][128 + uu]);
      }
      float rsc = res * cr - ims * sr - reo;
      float isc = res * sr + ims * cr - imo;
      sabs += sqrtf(rsc * rsc + isc * isc);
    }
    float srel = 0.f;
    #pragma unroll
    for (int u0 = 0; u0 < 128; u0 += 64) {
      int u = u0 + l;
      float dre = p[2 * r][u] - p[2 * r + 1][u];
      float dim = p[2 * r][128 + u] - p[2 * r + 1][128 + u];
      srel += sqrtf(dre * dre + dim * dim);
    }
    float tot = sabs + srel;
    #pragma unroll
    for (int off = 32; off > 0; off >>= 1) tot += __shfl_down(tot, off);
    if (l == 0) out[base_row + r] = GAMMA_C - tot;
  }
}

// ===========================================================================
// Fallback (no-workspace path): round-1 structure, inline sincos.
#define FNTH 256
#define FRPB 4

#define MV_CHUNK(AR, AI)                                                      \
  {                                                                           \
    const float* a0p = &Af[er_mv][kc];                                        \
    const float* a1p = &Af[er_mv][kc ^ 256];                                  \
    _Pragma("unroll")                                                         \
    for (int kk = 0; kk < 16; kk += 4) {                                      \
      float4 a0 = *(const float4*)(a0p + kk);                                 \
      float4 a1 = *(const float4*)(a1p + kk);                                 \
      _Pragma("unroll")                                                       \
      for (int q = 0; q < 4; ++q) {                                           \
        float av = (q == 0) ? a0.x : (q == 1) ? a0.y : (q == 2) ? a0.z : a0.w;\
        float bv = (q == 0) ? a1.x : (q == 1) ? a1.y : (q == 2) ? a1.z : a1.w;\
        float4 wq = *(const float4*)&Wc[kk + q][j0];                          \
        AR.x = fmaf(av, wq.x, AR.x); AR.y = fmaf(av, wq.y, AR.y);             \
        AR.z = fmaf(av, wq.z, AR.z); AR.w = fmaf(av, wq.w, AR.w);             \
        AI.x = fmaf(bv, wq.x, AI.x); AI.y = fmaf(bv, wq.y, AI.y);             \
        AI.z = fmaf(bv, wq.z, AI.z); AI.w = fmaf(bv, wq.w, AI.w);             \
      }                                                                       \
    }                                                                         \
  }

__global__ __launch_bounds__(FNTH) void kge_main_fb(
    const int* __restrict__ x,
    const float* __restrict__ e_emb, const float* __restrict__ r_emb,
    const float* __restrict__ d_frq, const float* __restrict__ d_phi, const float* __restrict__ d_amp,
    const float* __restrict__ m_frq, const float* __restrict__ m_phi, const float* __restrict__ m_amp,
    const float* __restrict__ w_e, const float* __restrict__ w_rp,
    float* __restrict__ out) {
  __shared__ __align__(16) float Af[2 * FRPB][512];
  __shared__ __align__(16) float st[2 * FRPB][256];
  __shared__ __align__(16) float p[2 * FRPB][256];
  __shared__ __align__(16) float Wc[16][128];
  __shared__ float wrp[FRPB][200];
  __shared__ unsigned short cs[FRPB][400];
  __shared__ int meta[FRPB][6];

  const int tid = threadIdx.x;
  const int base_row = blockIdx.x * FRPB;

  if (tid < FRPB * 6) {
    int r = tid / 6, f = tid % 6;
    meta[r][f] = x[(size_t)(base_row + r) * XSTR + f];
  }
  __syncthreads();
  for (int i = tid; i < 2 * FRPB * 128; i += FNTH) {
    int er = i >> 7, k4 = i & 127;
    int e = (er & 1) ? meta[er >> 1][2] : meta[er >> 1][0];
    ((float4*)Af)[i] = ((const float4*)e_emb)[(size_t)e * 128 + k4];
  }
  for (int i = tid; i < FRPB * 400; i += FNTH) {
    int r = i / 400, n = i - r * 400;
    cs[r][n] = (unsigned short)x[(size_t)(base_row + r) * XSTR + 6 + n];
  }
  for (int i = tid; i < FRPB * 200; i += FNTH) {
    int r = i / 200, n = i - r * 200;
    wrp[r][n] = w_rp[(size_t)meta[r][1] * 200 + n];
  }
  for (int it = tid; it < 2 * FRPB * 256; it += FNTH) {
    int j = it & 255, er = it >> 8, r = er >> 1;
    int e = (er & 1) ? meta[r][2] : meta[r][0];
    float dv = (float)meta[r][3], mv = (float)meta[r][4];
    size_t b256 = (size_t)e * 256 + j, b128 = (size_t)e * 128 + (j & 127);
    float argd = fmaf(dv, d_frq[b256], d_phi[b256]);
    float argm = fmaf(mv, m_frq[b256], m_phi[b256]);
    float vd = (j < 128) ? d_amp[b128] * cosf(argd) : d_amp[b128] * sinf(argd);
    float vm = (j < 128) ? m_amp[b128] * cosf(argm) : m_amp[b128] * sinf(argm);
    st[er][j] = vd + vm;
  }

  const int er_mv = tid >> 5;
  const int j0 = (tid & 31) * 4;
  float4 pRe = {0, 0, 0, 0}, pIm = {0, 0, 0, 0};
  float4 nRe = {0, 0, 0, 0}, nIm = {0, 0, 0, 0};
  for (int kc = 0; kc < 512; kc += 16) {
    __syncthreads();
    for (int i = tid; i < 512; i += FNTH)
      ((float4*)Wc)[i] = ((const float4*)w_e)[kc * 32 + i];
    __syncthreads();
    if (kc < 256) MV_CHUNK(pRe, pIm) else MV_CHUNK(nRe, nIm);
  }
  p[er_mv][j0 + 0] = pRe.x - nRe.x; p[er_mv][j0 + 1] = pRe.y - nRe.y;
  p[er_mv][j0 + 2] = pRe.z - nRe.z; p[er_mv][j0 + 3] = pRe.w - nRe.w;
  p[er_mv][128 + j0 + 0] = pIm.x - nIm.x; p[er_mv][128 + j0 + 1] = pIm.y - nIm.y;
  p[er_mv][128 + j0 + 2] = pIm.z - nIm.z; p[er_mv][128 + j0 + 3] = pIm.w - nIm.w;
  __syncthreads();

  const int wv = tid >> 6, l = tid & 63;
  for (int pass = 0; pass < 2; ++pass) {
    int er = wv + 4 * pass;
    int r = er >> 1, ent = er & 1;
    float acc0 = 0.f, acc1 = 0.f, acc2 = 0.f, acc3 = 0.f;
    float f0 = (float)pow(10000.0, -(double)(2 * l) / 128.0);
    float f1 = (float)pow(10000.0, -(double)(2 * l + 1) / 128.0);
    for (int n = 0; n < 200; ++n) {
      float c = (float)cs[r][ent * 200 + n];
      float wt = wrp[r][n];
      float sA, cA, sB, cB;
      sincosf(c * f0, &sA, &cA);
      sincosf(c * f1, &sB, &cB);
      acc0 = fmaf(wt, cA, acc0); acc1 = fmaf(wt, cB, acc1);
      acc2 = fmaf(wt, sA, acc2); acc3 = fmaf(wt, sB, acc3);
    }
    p[er][2 * l]       += acc0;
    p[er][2 * l + 1]   += acc1;
    p[er][128 + 2 * l] += acc2;
    p[er][129 + 2 * l] += acc3;
  }
  __syncthreads();

  {
    int r = wv;
    int rid = meta[r][1];
    float sabs = 0.f;
    for (int u = l; u < 384; u += 64) {
      float ang = r_emb[(size_t)rid * 384 + u] * SCALE_ANG;
      float sr, cr;
      sincosf(ang, &sr, &cr);
      float res, ims, reo, imo;
      if (u < 256) {
        res = Af[2 * r][u];     ims = Af[2 * r][256 + u];
        reo = Af[2 * r + 1][u]; imo = Af[2 * r + 1][256 + u];
      } else {
        int uu = u - 256;
        res = st[2 * r][uu];     ims = st[2 * r][128 + uu];
        reo = st[2 * r + 1][uu]; imo = st[2 * r + 1][128 + uu];
      }
      float rsc = res * cr - ims * sr - reo;
      float isc = res * sr + ims * cr - imo;
      sabs += sqrtf(rsc * rsc + isc * isc);
    }
    float srel = 0.f;
    for (int u = l; u < 128; u += 64) {
      float dre = p[2 * r][u] - p[2 * r + 1][u];
      float dim = p[2 * r][128 + u] - p[2 * r + 1][128 + u];
      srel += sqrtf(dre * dre + dim * dim);
    }
    float tot = sabs + srel;
    #pragma unroll
    for (int off = 32; off > 0; off >>= 1) tot += __shfl_down(tot, off);
    if (l == 0) out[base_row + r] = GAMMA_C - tot;
  }
}

// ===========================================================================
extern "C" void kernel_launch(void* const* d_in, const int* in_sizes, int n_in,
                              void* d_out, int out_size, void* d_ws, size_t ws_size,
                              hipStream_t stream) {
  (void)in_sizes; (void)n_in; (void)out_size;
  const int*   x     = (const int*)d_in[0];
  const float* e_emb = (const float*)d_in[1];
  const float* r_emb = (const float*)d_in[2];
  const float* d_frq = (const float*)d_in[3];
  const float* d_phi = (const float*)d_in[4];
  const float* d_amp = (const float*)d_in[5];
  const float* m_frq = (const float*)d_in[6];
  const float* m_phi = (const float*)d_in[7];
  const float* m_amp = (const float*)d_in[8];
  const float* w_e   = (const float*)d_in[9];
  const float* w_rp  = (const float*)d_in[10];
  float* out = (float*)d_out;

  if (ws_size >= WS_NEED) {
    unsigned short* tab  = (unsigned short*)d_ws;
    unsigned short* wcat = (unsigned short*)((char*)d_ws + TAB_BYTES);
    kge_table<<<dim3(1000), dim3(128), 0, stream>>>(tab);
    kge_wcat<<<dim3(256), dim3(64), 0, stream>>>(w_e, wcat);
    kge_main3<<<dim3(B_ROWS / RPB), dim3(NTH), 0, stream>>>(
        x, e_emb, r_emb, d_frq, d_phi, d_amp, m_frq, m_phi, m_amp, w_rp,
        tab, wcat, out);
  } else {
    kge_main_fb<<<dim3(B_ROWS / FRPB), dim3(FNTH), 0, stream>>>(
        x, e_emb, r_emb, d_frq, d_phi, d_amp, m_frq, m_phi, m_amp, w_e, w_rp, out);
  }
}

// Round 4
// 97.850 us; speedup vs baseline: 2.2463x; 1.4786x over previous
//
#include <hip/hip_runtime.h>
#include <cstdint>

// ---- problem constants ----
#define B_ROWS 8192
#define XSTR   406      // x row stride (ints)
#define GAMMA_C 12.0f
#define SCALE_ANG 30.994217f   // PI / sqrt(6/584)

// ---- config ----
#define NTH    512
#define RPB    8
#define ERB    (2*RPB)         // 16 entity rows / block
#define APAD   520             // A row stride in bf16 elems
#define KH     1024            // padded K (t-range 1000 -> 1024)

// workspace layout (full path)
#define TF_BYTES    (KH*256*2)         // 524288  : tab in B-frag order
#define WCAT_BYTES  (512*256*2)        // 262144  : sign-folded w_e in B-frag order
#define H_BYTES     (16384*KH*2)       // 33554432: histogram matrix bf16
#define P3_BYTES    (16384*256*4)      // 16777216: GEMM output f32
#define WS_FULL     ((size_t)(TF_BYTES + WCAT_BYTES + H_BYTES + P3_BYTES))
// workspace layout (round-3 fallback path)
#define OLDTAB_BYTES (1000*256*2)
#define WS_OLD       ((size_t)(OLDTAB_BYTES + WCAT_BYTES))

typedef __attribute__((ext_vector_type(8))) short short8v;
typedef __attribute__((ext_vector_type(4))) float float4v;

__device__ __forceinline__ float bfLo(uint32_t u) { return __uint_as_float(u << 16); }
__device__ __forceinline__ float bfHi(uint32_t u) { return __uint_as_float(u & 0xffff0000u); }
__device__ __forceinline__ float bf1(unsigned short u) { return __uint_as_float((uint32_t)u << 16); }

__device__ __forceinline__ uint32_t f2bf_u(float x) {
  uint32_t u = __float_as_uint(x);
  u += 0x7fffu + ((u >> 16) & 1u);   // RNE
  return u >> 16;
}
__device__ __forceinline__ unsigned short f2bf(float x) { return (unsigned short)f2bf_u(x); }

// ---------------------------------------------------------------------------
// Prep A: tab (KHx256) in MFMA B-frag order.
// value(k,c) = k<1000 ? (c<128 ? cos(k*f_c) : sin(k*f_{c-128})) : 0
// frag (kt 0..31, nt 0..15), lane l, elem j <-> k=kt*32+(l>>4)*8+j, c=nt*16+(l&15)
__global__ void kge_tabfrag(unsigned short* __restrict__ tf) {
  int bid = blockIdx.x;            // kt*16 + nt
  int nt = bid & 15;
  int kt = bid >> 4;
  int l = threadIdx.x;
  int c = nt * 16 + (l & 15);
  double f = pow(10000.0, -(double)(c & 127) / 128.0);
  __align__(16) unsigned short v[8];
  #pragma unroll
  for (int j = 0; j < 8; ++j) {
    int k = kt * 32 + ((l >> 4) << 3) + j;
    float val = 0.f;
    if (k < 1000) {
      double ang = (double)k * f;
      val = (c < 128) ? (float)cos(ang) : (float)sin(ang);
    }
    v[j] = f2bf(val);
  }
  ((uint4*)tf)[bid * 64 + l] = *(const uint4*)v;
}

// ---------------------------------------------------------------------------
// Prep B: sign-folded weights Wcat (512x256) in MFMA B-frag order (bf16).
__global__ void kge_wcat(const float* __restrict__ w_e, unsigned short* __restrict__ wcat) {
  int bid = blockIdx.x;            // kk*16 + nt
  int kk = bid >> 4, nt = bid & 15;
  int l = threadIdx.x;
  __align__(16) unsigned short v[8];
  int c = nt * 16 + (l & 15);
  #pragma unroll
  for (int j = 0; j < 8; ++j) {
    int k = kk * 32 + ((l >> 4) << 3) + j;
    float s = (k < 256) ? 1.f : -1.f;
    float val = (c < 128) ? s * w_e[k * 128 + c]
                          : -s * w_e[(k ^ 256) * 128 + (c - 128)];
    v[j] = f2bf(val);
  }
  ((uint4*)wcat)[bid * 64 + l] = *(const uint4*)v;
}

// ---------------------------------------------------------------------------
// H build: H[re][t] = sum_{n: c_{re,n}=t} w_rp[rid][n].  4 row-ents / block.
__global__ __launch_bounds__(256) void kge_hbuild(const int* __restrict__ x,
                                                  const float* __restrict__ w_rp,
                                                  unsigned short* __restrict__ H) {
  __shared__ float Hl[4][KH];
  const int w = threadIdx.x >> 6, l = threadIdx.x & 63;
  const int re = blockIdx.x * 4 + w;
  const int row = re >> 1, ent = re & 1;
  float4 z = {0, 0, 0, 0};
  for (int i = l; i < KH / 4; i += 64) ((float4*)Hl[w])[i] = z;
  const int rid = x[(size_t)row * XSTR + 1];
  const int* cp = x + (size_t)row * XSTR + 6 + ent * 200;
  const float* wp = w_rp + (size_t)rid * 200;
  for (int n = l; n < 200; n += 64)
    atomicAdd(&Hl[w][cp[n]], wp[n]);
  unsigned short* dst = H + (size_t)re * KH;
  for (int i = l; i < KH / 2; i += 64) {
    float a = Hl[w][2 * i], b = Hl[w][2 * i + 1];
    ((uint32_t*)dst)[i] = f2bf_u(a) | (f2bf_u(b) << 16);
  }
}

// ---------------------------------------------------------------------------
// GEMM: P3(16384x256,f32) = H(16384xKH,bf16) @ tab(KHx256,bf16)
// grid (128, 2): M-tile 128, N-tile 128. 8 waves; wave w -> rows [w*16, w*16+16).
__global__ __launch_bounds__(512) void kge_gemm(const unsigned short* __restrict__ H,
                                                const unsigned short* __restrict__ tf,
                                                float* __restrict__ P3) {
  __shared__ __align__(16) unsigned short bb[8 * 64 * 8];   // 8 frags = 8 KB
  const int tid = threadIdx.x;
  const int w = tid >> 6, l = tid & 63;
  const int m0 = blockIdx.x * 128 + w * 16;
  const int nb = blockIdx.y;                 // 0/1 -> cols nb*128..+128
  float4v acc[8];
  #pragma unroll
  for (int i = 0; i < 8; ++i) acc[i] = (float4v){0, 0, 0, 0};

  const unsigned short* arow = H + (size_t)(m0 + (l & 15)) * KH + ((l >> 4) << 3);
  for (int kt = 0; kt < 32; ++kt) {
    short8v a = *(const short8v*)(arow + kt * 32);
    __syncthreads();   // previous iter's ds_reads done before overwrite
    // stage 8 B-frags for (kt, nb): thread i copies frag (i>>6), lane (i&63)
    ((uint4*)bb)[tid] = ((const uint4*)tf)[(kt * 16 + nb * 8 + (tid >> 6)) * 64 + (tid & 63)];
    __syncthreads();
    #pragma unroll
    for (int nt = 0; nt < 8; ++nt) {
      short8v b = *(const short8v*)&bb[(nt * 64 + l) * 8];
      acc[nt] = __builtin_amdgcn_mfma_f32_16x16x32_bf16(a, b, acc[nt], 0, 0, 0);
    }
  }
  const int col0 = nb * 128 + (l & 15);
  const int r0 = m0 + ((l >> 4) << 2);
  #pragma unroll
  for (int nt = 0; nt < 8; ++nt)
    #pragma unroll
    for (int q = 0; q < 4; ++q)
      P3[(size_t)(r0 + q) * 256 + col0 + nt * 16] = acc[nt][q];
}

// ---------------------------------------------------------------------------
// Main fused kernel: staging + t_emb + e_p_emb MFMA + P3 merge + scores
__global__ __launch_bounds__(NTH, 4) void kge_main4(
    const int* __restrict__ x,
    const float* __restrict__ e_emb, const float* __restrict__ r_emb,
    const float* __restrict__ d_frq, const float* __restrict__ d_phi, const float* __restrict__ d_amp,
    const float* __restrict__ m_frq, const float* __restrict__ m_phi, const float* __restrict__ m_amp,
    const unsigned short* __restrict__ wcat, const float* __restrict__ P3,
    float* __restrict__ out) {
  __shared__ __align__(16) unsigned short A[ERB][APAD];
  __shared__ __align__(16) unsigned short stb[ERB][256];
  __shared__ __align__(16) float p[ERB][256];
  __shared__ int meta[RPB][6];

  const int tid = threadIdx.x;
  const int base_row = blockIdx.x * RPB;
  const int w = tid >> 6, l = tid & 63;

  if (tid < RPB * 6) {
    int r = tid / 6, f = tid % 6;
    meta[r][f] = x[(size_t)(base_row + r) * XSTR + f];
  }
  __syncthreads();

  // ---- gather e_emb rows -> A (bf16) ----
  for (int i = tid; i < ERB * 128; i += NTH) {
    int er = i >> 7, k4 = i & 127;
    int e = (er & 1) ? meta[er >> 1][2] : meta[er >> 1][0];
    float4 v = ((const float4*)e_emb)[(size_t)e * 128 + k4];
    uint2 pk;
    pk.x = f2bf_u(v.x) | (f2bf_u(v.y) << 16);
    pk.y = f2bf_u(v.z) | (f2bf_u(v.w) << 16);
    *(uint2*)&A[er][k4 * 4] = pk;
  }
  // ---- t_emb -> stb (float2 loads, native trig) ----
  for (int it = tid; it < ERB * 128; it += NTH) {
    int jj = it & 127, er = it >> 7, r = er >> 1;
    int e = (er & 1) ? meta[r][2] : meta[r][0];
    float dv = (float)meta[r][3], mv = (float)meta[r][4];
    int j = 2 * jj;
    float2 fd = *(const float2*)&d_frq[(size_t)e * 256 + j];
    float2 pd = *(const float2*)&d_phi[(size_t)e * 256 + j];
    float2 fm = *(const float2*)&m_frq[(size_t)e * 256 + j];
    float2 pm = *(const float2*)&m_phi[(size_t)e * 256 + j];
    int ja = j & 127;
    float2 ad = *(const float2*)&d_amp[(size_t)e * 128 + ja];
    float2 am = *(const float2*)&m_amp[(size_t)e * 128 + ja];
    float a0 = fmaf(dv, fd.x, pd.x), a1 = fmaf(dv, fd.y, pd.y);
    float b0 = fmaf(mv, fm.x, pm.x), b1 = fmaf(mv, fm.y, pm.y);
    float t0, t1, u0, u1;
    if (j < 128) { t0 = __cosf(a0); t1 = __cosf(a1); u0 = __cosf(b0); u1 = __cosf(b1); }
    else         { t0 = __sinf(a0); t1 = __sinf(a1); u0 = __sinf(b0); u1 = __sinf(b1); }
    float v0 = fmaf(ad.x, t0, am.x * u0);
    float v1 = fmaf(ad.y, t1, am.y * u1);
    *(uint32_t*)&stb[er][j] = f2bf_u(v0) | (f2bf_u(v1) << 16);
  }
  __syncthreads();

  // ---- e_p_emb: p = A @ Wcat via MFMA (wave w owns col tiles 2w, 2w+1) ----
  {
    float4v acc0 = {0, 0, 0, 0}, acc1 = {0, 0, 0, 0};
    const int nt0 = 2 * w, nt1 = 2 * w + 1;
    const short8v* bp = (const short8v*)wcat;
    const unsigned short* arow = &A[l & 15][(l >> 4) << 3];
    #pragma unroll 8
    for (int kk = 0; kk < 16; ++kk) {
      short8v a  = *(const short8v*)(arow + kk * 32);
      short8v b0 = bp[(kk * 16 + nt0) * 64 + l];
      short8v b1 = bp[(kk * 16 + nt1) * 64 + l];
      acc0 = __builtin_amdgcn_mfma_f32_16x16x32_bf16(a, b0, acc0, 0, 0, 0);
      acc1 = __builtin_amdgcn_mfma_f32_16x16x32_bf16(a, b1, acc1, 0, 0, 0);
    }
    int col = l & 15, rbase = (l >> 4) * 4;
    #pragma unroll
    for (int q = 0; q < 4; ++q) {
      p[rbase + q][nt0 * 16 + col] = acc0[q];
      p[rbase + q][nt1 * 16 + col] = acc1[q];
    }
  }
  __syncthreads();

  // ---- merge P3 (e_r_emb) into p: wave w owns rows 2w, 2w+1 ----
  {
    int re_s = (base_row + w) * 2;
    float4 vs = ((const float4*)(P3 + (size_t)re_s * 256))[l];
    float4 vo = ((const float4*)(P3 + (size_t)(re_s + 1) * 256))[l];
    int es = 2 * w, eo = 2 * w + 1, c = 4 * l;
    p[es][c] += vs.x; p[es][c + 1] += vs.y; p[es][c + 2] += vs.z; p[es][c + 3] += vs.w;
    p[eo][c] += vo.x; p[eo][c + 1] += vo.y; p[eo][c + 2] += vo.z; p[eo][c + 3] += vo.w;
  }
  __syncthreads();

  // ---- scores (wave w -> row w) ----
  {
    int r = w;
    int rid = meta[r][1];
    float sabs = 0.f;
    #pragma unroll
    for (int u0 = 0; u0 < 384; u0 += 64) {
      int u = u0 + l;
      float ang = r_emb[(size_t)rid * 384 + u] * SCALE_ANG;
      float sr = __sinf(ang), cr = __cosf(ang);
      float res, ims, reo, imo;
      if (u < 256) {
        res = bf1(A[2 * r][u]);       ims = bf1(A[2 * r][256 + u]);
        reo = bf1(A[2 * r + 1][u]);   imo = bf1(A[2 * r + 1][256 + u]);
      } else {
        int uu = u - 256;
        res = bf1(stb[2 * r][uu]);     ims = bf1(stb[2 * r][128 + uu]);
        reo = bf1(stb[2 * r + 1][uu]); imo = bf1(stb[2 * r + 1][128 + uu]);
      }
      float rsc = res * cr - ims * sr - reo;
      float isc = res * sr + ims * cr - imo;
      sabs += sqrtf(rsc * rsc + isc * isc);
    }
    float srel = 0.f;
    #pragma unroll
    for (int u0 = 0; u0 < 128; u0 += 64) {
      int u = u0 + l;
      float dre = p[2 * r][u] - p[2 * r + 1][u];
      float dim = p[2 * r][128 + u] - p[2 * r + 1][128 + u];
      srel += sqrtf(dre * dre + dim * dim);
    }
    float tot = sabs + srel;
    #pragma unroll
    for (int off = 32; off > 0; off >>= 1) tot += __shfl_down(tot, off);
    if (l == 0) out[base_row + r] = GAMMA_C - tot;
  }
}

// ===========================================================================
// Round-3 fallback path (workspace >= 774 KB but < 51 MB)
__global__ void kge_table_old(unsigned short* __restrict__ tab) {
  int t = blockIdx.x;
  int j = threadIdx.x;
  double f = pow(10000.0, -(double)j / 128.0);
  double ang = (double)t * f;
  int q = j >> 1, lo = j & 1;
  tab[t * 256 + 4 * q + lo]     = f2bf((float)cos(ang));
  tab[t * 256 + 4 * q + 2 + lo] = f2bf((float)sin(ang));
}

__global__ __launch_bounds__(NTH, 4) void kge_main3(
    const int* __restrict__ x,
    const float* __restrict__ e_emb, const float* __restrict__ r_emb,
    const float* __restrict__ d_frq, const float* __restrict__ d_phi, const float* __restrict__ d_amp,
    const float* __restrict__ m_frq, const float* __restrict__ m_phi, const float* __restrict__ m_amp,
    const float* __restrict__ w_rp,
    const unsigned short* __restrict__ tab, const unsigned short* __restrict__ wcat,
    float* __restrict__ out) {
  __shared__ __align__(16) unsigned short A[ERB][APAD];
  __shared__ __align__(16) unsigned short stb[ERB][256];
  __shared__ __align__(16) float p[ERB][256];
  __shared__ int meta[RPB][6];

  const int tid = threadIdx.x;
  const int base_row = blockIdx.x * RPB;
  const int w = tid >> 6, l = tid & 63;

  if (tid < RPB * 6) {
    int r = tid / 6, f = tid % 6;
    meta[r][f] = x[(size_t)(base_row + r) * XSTR + f];
  }
  __syncthreads();

  for (int i = tid; i < ERB * 128; i += NTH) {
    int er = i >> 7, k4 = i & 127;
    int e = (er & 1) ? meta[er >> 1][2] : meta[er >> 1][0];
    float4 v = ((const float4*)e_emb)[(size_t)e * 128 + k4];
    uint2 pk;
    pk.x = f2bf_u(v.x) | (f2bf_u(v.y) << 16);
    pk.y = f2bf_u(v.z) | (f2bf_u(v.w) << 16);
    *(uint2*)&A[er][k4 * 4] = pk;
  }
  for (int it = tid; it < ERB * 256; it += NTH) {
    int j = it & 255, er = it >> 8, r = er >> 1;
    int e = (er & 1) ? meta[r][2] : meta[r][0];
    float dv = (float)meta[r][3], mv = (float)meta[r][4];
    size_t b256 = (size_t)e * 256 + j, b128 = (size_t)e * 128 + (j & 127);
    float argd = fmaf(dv, d_frq[b256], d_phi[b256]);
    float argm = fmaf(mv, m_frq[b256], m_phi[b256]);
    float vd = (j < 128) ? d_amp[b128] * __cosf(argd) : d_amp[b128] * __sinf(argd);
    float vm = (j < 128) ? m_amp[b128] * __cosf(argm) : m_amp[b128] * __sinf(argm);
    stb[er][j] = f2bf(vd + vm);
  }

  float s0 = 0, s1 = 0, s2 = 0, s3 = 0, o0 = 0, o1 = 0, o2 = 0, o3 = 0;
  {
    const int wu  = __builtin_amdgcn_readfirstlane(w);
    const int rid = __builtin_amdgcn_readfirstlane(meta[wu][1]);
    const int*   cp = x + (size_t)(base_row + wu) * XSTR + 6;
    const float* wp = w_rp + (size_t)rid * 200;
    const uint2* tl = ((const uint2*)tab) + l;
    #pragma unroll 2
    for (int n = 0; n < 200; ++n) {
      float wv = wp[n];
      int cS = cp[n];
      int cO = cp[200 + n];
      uint2 qs = tl[(size_t)cS * 64];
      uint2 qo = tl[(size_t)cO * 64];
      s0 = fmaf(wv, bfLo(qs.x), s0); s1 = fmaf(wv, bfHi(qs.x), s1);
      s2 = fmaf(wv, bfLo(qs.y), s2); s3 = fmaf(wv, bfHi(qs.y), s3);
      o0 = fmaf(wv, bfLo(qo.x), o0); o1 = fmaf(wv, bfHi(qo.x), o1);
      o2 = fmaf(wv, bfLo(qo.y), o2); o3 = fmaf(wv, bfHi(qo.y), o3);
    }
  }
  __syncthreads();

  {
    float4v acc0 = {0, 0, 0, 0}, acc1 = {0, 0, 0, 0};
    const int nt0 = 2 * w, nt1 = 2 * w + 1;
    const short8v* bp = (const short8v*)wcat;
    const unsigned short* arow = &A[l & 15][(l >> 4) << 3];
    #pragma unroll 8
    for (int kk = 0; kk < 16; ++kk) {
      short8v a  = *(const short8v*)(arow + kk * 32);
      short8v b0 = bp[(kk * 16 + nt0) * 64 + l];
      short8v b1 = bp[(kk * 16 + nt1) * 64 + l];
      acc0 = __builtin_amdgcn_mfma_f32_16x16x32_bf16(a, b0, acc0, 0, 0, 0);
      acc1 = __builtin_amdgcn_mfma_f32_16x16x32_bf16(a, b1, acc1, 0, 0, 0);
    }
    int col = l & 15, rbase = (l >> 4) * 4;
    #pragma unroll
    for (int q = 0; q < 4; ++q) {
      p[rbase + q][nt0 * 16 + col] = acc0[q];
      p[rbase + q][nt1 * 16 + col] = acc1[q];
    }
  }
  __syncthreads();

  {
    int es = 2 * w, eo = 2 * w + 1;
    p[es][2 * l] += s0; p[es][2 * l + 1] += s1;
    p[es][128 + 2 * l] += s2; p[es][129 + 2 * l] += s3;
    p[eo][2 * l] += o0; p[eo][2 * l + 1] += o1;
    p[eo][128 + 2 * l] += o2; p[eo][129 + 2 * l] += o3;
  }
  __syncthreads();

  {
    int r = w;
    int rid = meta[r][1];
    float sabs = 0.f;
    #pragma unroll
    for (int u0 = 0; u0 < 384; u0 += 64) {
      int u = u0 + l;
      float ang = r_emb[(size_t)rid * 384 + u] * SCALE_ANG;
      float sr = __sinf(ang), cr = __cosf(ang);
      float res, ims, reo, imo;
      if (u < 256) {
        res = bf1(A[2 * r][u]);       ims = bf1(A[2 * r][256 + u]);
        reo = bf1(A[2 * r + 1][u]);   imo = bf1(A[2 * r + 1][256 + u]);
      } else {
        int uu = u - 256;
        res = bf1(stb[2 * r][uu]);     ims = bf1(stb[2 * r][128 + uu]);
        reo = bf1(stb[2 * r + 1][uu]); imo = bf1(stb[2 * r + 1][128 + uu]);
      }
      float rsc = res * cr - ims * sr - reo;
      float isc = res * sr + ims * cr - imo;
      sabs += sqrtf(rsc * rsc + isc * isc);
    }
    float srel = 0.f;
    #pragma unroll
    for (int u0 = 0; u0 < 128; u0 += 64) {
      int u = u0 + l;
      float dre = p[2 * r][u] - p[2 * r + 1][u];
      float dim = p[2 * r][128 + u] - p[2 * r + 1][128 + u];
      srel += sqrtf(dre * dre + dim * dim);
    }
    float tot = sabs + srel;
    #pragma unroll
    for (int off = 32; off > 0; off >>= 1) tot += __shfl_down(tot, off);
    if (l == 0) out[base_row + r] = GAMMA_C - tot;
  }
}

// ===========================================================================
extern "C" void kernel_launch(void* const* d_in, const int* in_sizes, int n_in,
                              void* d_out, int out_size, void* d_ws, size_t ws_size,
                              hipStream_t stream) {
  (void)in_sizes; (void)n_in; (void)out_size;
  const int*   x     = (const int*)d_in[0];
  const float* e_emb = (const float*)d_in[1];
  const float* r_emb = (const float*)d_in[2];
  const float* d_frq = (const float*)d_in[3];
  const float* d_phi = (const float*)d_in[4];
  const float* d_amp = (const float*)d_in[5];
  const float* m_frq = (const float*)d_in[6];
  const float* m_phi = (const float*)d_in[7];
  const float* m_amp = (const float*)d_in[8];
  const float* w_e   = (const float*)d_in[9];
  const float* w_rp  = (const float*)d_in[10];
  float* out = (float*)d_out;

  if (ws_size >= WS_FULL) {
    unsigned short* tf   = (unsigned short*)d_ws;
    unsigned short* wcat = (unsigned short*)((char*)d_ws + TF_BYTES);
    unsigned short* H    = (unsigned short*)((char*)d_ws + TF_BYTES + WCAT_BYTES);
    float*          P3   = (float*)((char*)d_ws + TF_BYTES + WCAT_BYTES + H_BYTES);
    kge_tabfrag<<<dim3(512), dim3(64), 0, stream>>>(tf);
    kge_wcat<<<dim3(256), dim3(64), 0, stream>>>(w_e, wcat);
    kge_hbuild<<<dim3(16384 / 4), dim3(256), 0, stream>>>(x, w_rp, H);
    kge_gemm<<<dim3(128, 2), dim3(512), 0, stream>>>(H, tf, P3);
    kge_main4<<<dim3(B_ROWS / RPB), dim3(NTH), 0, stream>>>(
        x, e_emb, r_emb, d_frq, d_phi, d_amp, m_frq, m_phi, m_amp,
        wcat, P3, out);
  } else if (ws_size >= WS_OLD) {
    unsigned short* tab  = (unsigned short*)d_ws;
    unsigned short* wcat = (unsigned short*)((char*)d_ws + OLDTAB_BYTES);
    kge_table_old<<<dim3(1000), dim3(128), 0, stream>>>(tab);
    kge_wcat<<<dim3(256), dim3(64), 0, stream>>>(w_e, wcat);
    kge_main3<<<dim3(B_ROWS / RPB), dim3(NTH), 0, stream>>>(
        x, e_emb, r_emb, d_frq, d_phi, d_amp, m_frq, m_phi, m_amp, w_rp,
        tab, wcat, out);
  }
}

// Round 5
// 84.997 us; speedup vs baseline: 2.5859x; 1.1512x over previous
//
#include <hip/hip_runtime.h>
#include <cstdint>

// ---- problem constants ----
#define B_ROWS 8192
#define XSTR   406      // x row stride (ints)
#define GAMMA_C 12.0f
#define SCALE_ANG 30.994217f   // PI / sqrt(6/584)

// ---- config ----
#define NTH    512
#define RPB    8
#define ERB    (2*RPB)         // 16 entity rows / block
#define APAD   520             // A row stride in bf16 elems
#define KH     1024            // padded K (t-range 1000 -> 1024)

// prep grid partition
#define NH_BLK 4096            // hbuild: 4 row-ents/block
#define NT_BLK 128             // tabfrag: 4 frags/block (512 frags)
#define NW_BLK 64              // wcat: 4 frags/block (256 frags)

// workspace layout (full path)
#define TF_BYTES    (KH*256*2)         // 524288  : tab in B-frag order
#define WCAT_BYTES  (512*256*2)        // 262144  : sign-folded w_e in B-frag order
#define H_BYTES     (16384*KH*2)       // 33554432: histogram matrix bf16
#define P3_BYTES    (16384*256*4)      // 16777216: GEMM output f32
#define WS_FULL     ((size_t)(TF_BYTES + WCAT_BYTES + H_BYTES + P3_BYTES))
// workspace layout (round-3 fallback path)
#define OLDTAB_BYTES (1000*256*2)
#define WS_OLD       ((size_t)(OLDTAB_BYTES + WCAT_BYTES))

typedef __attribute__((ext_vector_type(8))) short short8v;
typedef __attribute__((ext_vector_type(4))) float float4v;

__device__ __forceinline__ float bfLo(uint32_t u) { return __uint_as_float(u << 16); }
__device__ __forceinline__ float bfHi(uint32_t u) { return __uint_as_float(u & 0xffff0000u); }
__device__ __forceinline__ float bf1(unsigned short u) { return __uint_as_float((uint32_t)u << 16); }

__device__ __forceinline__ uint32_t f2bf_u(float x) {
  uint32_t u = __float_as_uint(x);
  u += 0x7fffu + ((u >> 16) & 1u);   // RNE
  return u >> 16;
}
__device__ __forceinline__ unsigned short f2bf(float x) { return (unsigned short)f2bf_u(x); }

// ---------------------------------------------------------------------------
// Merged prep: [0, NH_BLK) hbuild | [NH_BLK, +NT_BLK) tabfrag | rest wcat.
// B-frag swizzle: frag id fb, lane l, elem j <-> k = (fb>>4)*32+(l>>4)*8+j,
//                 c = (fb&15)*16 + (l&15)
__global__ __launch_bounds__(256) void kge_prep(
    const int* __restrict__ x, const float* __restrict__ w_rp,
    const float* __restrict__ w_e,
    unsigned short* __restrict__ tf, unsigned short* __restrict__ wcat,
    unsigned short* __restrict__ H) {
  __shared__ float Hl[4][KH];
  const int bid = blockIdx.x;
  const int tid = threadIdx.x;
  const int sub = tid >> 6, l = tid & 63;

  if (bid < NH_BLK) {
    // ---- H build: H[re][t] = sum_{n: c_{re,n}=t} w_rp[rid][n], wave-local ----
    const int re = bid * 4 + sub;
    const int row = re >> 1, ent = re & 1;
    float4 z = {0, 0, 0, 0};
    for (int i = l; i < KH / 4; i += 64) ((float4*)Hl[sub])[i] = z;
    const int rid = x[(size_t)row * XSTR + 1];
    const int* cp = x + (size_t)row * XSTR + 6 + ent * 200;
    const float* wp = w_rp + (size_t)rid * 200;
    for (int n = l; n < 200; n += 64)
      atomicAdd(&Hl[sub][cp[n]], wp[n]);
    unsigned short* dst = H + (size_t)re * KH;
    for (int i = l; i < KH / 2; i += 64) {
      float a = Hl[sub][2 * i], b = Hl[sub][2 * i + 1];
      ((uint32_t*)dst)[i] = f2bf_u(a) | (f2bf_u(b) << 16);
    }
  } else if (bid < NH_BLK + NT_BLK) {
    // ---- tab frags (f32 trig): value(k,c) = k<1000 ? cos/sin(k*f_{c&127}) : 0
    const int fragid = (bid - NH_BLK) * 4 + sub;     // 0..511 = kt*16+nt
    const int kt = fragid >> 4, nt = fragid & 15;
    const int c = nt * 16 + (l & 15);
    const float f = exp2f(-(float)(c & 127) * (13.287712379549449f / 128.f));
    __align__(16) unsigned short v[8];
    #pragma unroll
    for (int j = 0; j < 8; ++j) {
      int k = kt * 32 + ((l >> 4) << 3) + j;
      float val = 0.f;
      if (k < 1000) {
        float s, cv;
        sincosf((float)k * f, &s, &cv);
        val = (c < 128) ? cv : s;
      }
      v[j] = f2bf(val);
    }
    ((uint4*)tf)[fragid * 64 + l] = *(const uint4*)v;
  } else {
    // ---- Wcat frags: Wcat[k][c] = c<128 ? s(k)*w_e[k][c] : -s(k)*w_e[k^256][c-128]
    const int fragid = (bid - NH_BLK - NT_BLK) * 4 + sub;  // 0..255 = kk*16+nt
    const int kk = fragid >> 4, nt = fragid & 15;
    const int c = nt * 16 + (l & 15);
    __align__(16) unsigned short v[8];
    #pragma unroll
    for (int j = 0; j < 8; ++j) {
      int k = kk * 32 + ((l >> 4) << 3) + j;
      float s = (k < 256) ? 1.f : -1.f;
      float val = (c < 128) ? s * w_e[k * 128 + c]
                            : -s * w_e[(k ^ 256) * 128 + (c - 128)];
      v[j] = f2bf(val);
    }
    ((uint4*)wcat)[fragid * 64 + l] = *(const uint4*)v;
  }
}

// ---------------------------------------------------------------------------
// GEMM: P3(16384x256,f32) = H(16384xKH,bf16) @ tab(KHx256,bf16)
// grid (128, 2). M-tile 128 (8 waves x 16 rows), N-tile 128.
// Double-buffered B staging, ONE barrier per K-step (iter kt reads bb[kt&1],
// writes bb[kt&1^1]; readers of that buffer passed the barrier already).
__global__ __launch_bounds__(512) void kge_gemm(const unsigned short* __restrict__ H,
                                                const unsigned short* __restrict__ tf,
                                                float* __restrict__ P3) {
  __shared__ __align__(16) uint4 bb[2][512];   // 2 x 8 frags x 64 lanes = 16 KB
  const int tid = threadIdx.x;
  const int w = tid >> 6, l = tid & 63;
  const int m0 = blockIdx.x * 128 + w * 16;
  const int nb = blockIdx.y;
  float4v acc[8];
  #pragma unroll
  for (int i = 0; i < 8; ++i) acc[i] = (float4v){0, 0, 0, 0};

  const uint4* tfq = (const uint4*)tf;
  const int fsub = tid >> 6, flane = tid & 63;    // staged frag, lane
  const unsigned short* arow = H + (size_t)(m0 + (l & 15)) * KH + ((l >> 4) << 3);

  // prologue: stage kt=0
  bb[0][tid] = tfq[(size_t)(0 * 16 + nb * 8 + fsub) * 64 + flane];
  for (int kt = 0; kt < 32; ++kt) {
    const int cur = kt & 1;
    uint4 rg;
    if (kt < 31) rg = tfq[(size_t)((kt + 1) * 16 + nb * 8 + fsub) * 64 + flane];
    __syncthreads();
    short8v a = *(const short8v*)(arow + kt * 32);
    #pragma unroll
    for (int nt = 0; nt < 8; ++nt) {
      short8v b = *(const short8v*)&bb[cur][nt * 64 + l];
      acc[nt] = __builtin_amdgcn_mfma_f32_16x16x32_bf16(a, b, acc[nt], 0, 0, 0);
    }
    if (kt < 31) bb[cur ^ 1][tid] = rg;
  }
  const int col0 = nb * 128 + (l & 15);
  const int r0 = m0 + ((l >> 4) << 2);
  #pragma unroll
  for (int nt = 0; nt < 8; ++nt)
    #pragma unroll
    for (int q = 0; q < 4; ++q)
      P3[(size_t)(r0 + q) * 256 + col0 + nt * 16] = acc[nt][q];
}

// ---------------------------------------------------------------------------
// Main fused kernel: staging + t_emb + e_p_emb MFMA + P3 merge + scores
__global__ __launch_bounds__(NTH, 4) void kge_main4(
    const int* __restrict__ x,
    const float* __restrict__ e_emb, const float* __restrict__ r_emb,
    const float* __restrict__ d_frq, const float* __restrict__ d_phi, const float* __restrict__ d_amp,
    const float* __restrict__ m_frq, const float* __restrict__ m_phi, const float* __restrict__ m_amp,
    const unsigned short* __restrict__ wcat, const float* __restrict__ P3,
    float* __restrict__ out) {
  __shared__ __align__(16) unsigned short A[ERB][APAD];
  __shared__ __align__(16) unsigned short stb[ERB][256];
  __shared__ __align__(16) float p[ERB][256];
  __shared__ int meta[RPB][6];

  const int tid = threadIdx.x;
  const int base_row = blockIdx.x * RPB;
  const int w = tid >> 6, l = tid & 63;

  if (tid < RPB * 6) {
    int r = tid / 6, f = tid % 6;
    meta[r][f] = x[(size_t)(base_row + r) * XSTR + f];
  }
  // ---- prefetch P3 merge rows early (hide latency under t_emb + MFMA) ----
  const int re_s = (base_row + w) * 2;
  const float4 vs = ((const float4*)(P3 + (size_t)re_s * 256))[l];
  const float4 vo = ((const float4*)(P3 + (size_t)(re_s + 1) * 256))[l];
  __syncthreads();

  // ---- gather e_emb rows -> A (bf16) ----
  for (int i = tid; i < ERB * 128; i += NTH) {
    int er = i >> 7, k4 = i & 127;
    int e = (er & 1) ? meta[er >> 1][2] : meta[er >> 1][0];
    float4 v = ((const float4*)e_emb)[(size_t)e * 128 + k4];
    uint2 pk;
    pk.x = f2bf_u(v.x) | (f2bf_u(v.y) << 16);
    pk.y = f2bf_u(v.z) | (f2bf_u(v.w) << 16);
    *(uint2*)&A[er][k4 * 4] = pk;
  }
  // ---- t_emb -> stb (float2 loads, native trig) ----
  for (int it = tid; it < ERB * 128; it += NTH) {
    int jj = it & 127, er = it >> 7, r = er >> 1;
    int e = (er & 1) ? meta[r][2] : meta[r][0];
    float dv = (float)meta[r][3], mv = (float)meta[r][4];
    int j = 2 * jj;
    float2 fd = *(const float2*)&d_frq[(size_t)e * 256 + j];
    float2 pd = *(const float2*)&d_phi[(size_t)e * 256 + j];
    float2 fm = *(const float2*)&m_frq[(size_t)e * 256 + j];
    float2 pm = *(const float2*)&m_phi[(size_t)e * 256 + j];
    int ja = j & 127;
    float2 ad = *(const float2*)&d_amp[(size_t)e * 128 + ja];
    float2 am = *(const float2*)&m_amp[(size_t)e * 128 + ja];
    float a0 = fmaf(dv, fd.x, pd.x), a1 = fmaf(dv, fd.y, pd.y);
    float b0 = fmaf(mv, fm.x, pm.x), b1 = fmaf(mv, fm.y, pm.y);
    float t0, t1, u0, u1;
    if (j < 128) { t0 = __cosf(a0); t1 = __cosf(a1); u0 = __cosf(b0); u1 = __cosf(b1); }
    else         { t0 = __sinf(a0); t1 = __sinf(a1); u0 = __sinf(b0); u1 = __sinf(b1); }
    float v0 = fmaf(ad.x, t0, am.x * u0);
    float v1 = fmaf(ad.y, t1, am.y * u1);
    *(uint32_t*)&stb[er][j] = f2bf_u(v0) | (f2bf_u(v1) << 16);
  }
  __syncthreads();

  // ---- e_p_emb: p = A @ Wcat via MFMA (wave w owns col tiles 2w, 2w+1) ----
  {
    float4v acc0 = {0, 0, 0, 0}, acc1 = {0, 0, 0, 0};
    const int nt0 = 2 * w, nt1 = 2 * w + 1;
    const short8v* bp = (const short8v*)wcat;
    const unsigned short* arow = &A[l & 15][(l >> 4) << 3];
    #pragma unroll 8
    for (int kk = 0; kk < 16; ++kk) {
      short8v a  = *(const short8v*)(arow + kk * 32);
      short8v b0 = bp[(kk * 16 + nt0) * 64 + l];
      short8v b1 = bp[(kk * 16 + nt1) * 64 + l];
      acc0 = __builtin_amdgcn_mfma_f32_16x16x32_bf16(a, b0, acc0, 0, 0, 0);
      acc1 = __builtin_amdgcn_mfma_f32_16x16x32_bf16(a, b1, acc1, 0, 0, 0);
    }
    int col = l & 15, rbase = (l >> 4) * 4;
    #pragma unroll
    for (int q = 0; q < 4; ++q) {
      p[rbase + q][nt0 * 16 + col] = acc0[q];
      p[rbase + q][nt1 * 16 + col] = acc1[q];
    }
  }
  __syncthreads();

  // ---- merge prefetched P3 (e_r_emb) into p: wave w owns rows 2w, 2w+1 ----
  {
    int es = 2 * w, eo = 2 * w + 1, c = 4 * l;
    p[es][c] += vs.x; p[es][c + 1] += vs.y; p[es][c + 2] += vs.z; p[es][c + 3] += vs.w;
    p[eo][c] += vo.x; p[eo][c + 1] += vo.y; p[eo][c + 2] += vo.z; p[eo][c + 3] += vo.w;
  }
  __syncthreads();

  // ---- scores (wave w -> row w) ----
  {
    int r = w;
    int rid = meta[r][1];
    float sabs = 0.f;
    #pragma unroll
    for (int u0 = 0; u0 < 384; u0 += 64) {
      int u = u0 + l;
      float ang = r_emb[(size_t)rid * 384 + u] * SCALE_ANG;
      float sr = __sinf(ang), cr = __cosf(ang);
      float res, ims, reo, imo;
      if (u < 256) {
        res = bf1(A[2 * r][u]);       ims = bf1(A[2 * r][256 + u]);
        reo = bf1(A[2 * r + 1][u]);   imo = bf1(A[2 * r + 1][256 + u]);
      } else {
        int uu = u - 256;
        res = bf1(stb[2 * r][uu]);     ims = bf1(stb[2 * r][128 + uu]);
        reo = bf1(stb[2 * r + 1][uu]); imo = bf1(stb[2 * r + 1][128 + uu]);
      }
      float rsc = res * cr - ims * sr - reo;
      float isc = res * sr + ims * cr - imo;
      sabs += sqrtf(rsc * rsc + isc * isc);
    }
    float srel = 0.f;
    #pragma unroll
    for (int u0 = 0; u0 < 128; u0 += 64) {
      int u = u0 + l;
      float dre = p[2 * r][u] - p[2 * r + 1][u];
      float dim = p[2 * r][128 + u] - p[2 * r + 1][128 + u];
      srel += sqrtf(dre * dre + dim * dim);
    }
    float tot = sabs + srel;
    #pragma unroll
    for (int off = 32; off > 0; off >>= 1) tot += __shfl_down(tot, off);
    if (l == 0) out[base_row + r] = GAMMA_C - tot;
  }
}

// ===========================================================================
// Round-3 fallback path (workspace >= 774 KB but < 51 MB)
__global__ void kge_table_old(unsigned short* __restrict__ tab) {
  int t = blockIdx.x;
  int j = threadIdx.x;
  double f = pow(10000.0, -(double)j / 128.0);
  double ang = (double)t * f;
  int q = j >> 1, lo = j & 1;
  tab[t * 256 + 4 * q + lo]     = f2bf((float)cos(ang));
  tab[t * 256 + 4 * q + 2 + lo] = f2bf((float)sin(ang));
}

__global__ void kge_wcat_old(const float* __restrict__ w_e, unsigned short* __restrict__ wcat) {
  int bid = blockIdx.x;
  int kk = bid >> 4, nt = bid & 15;
  int l = threadIdx.x;
  __align__(16) unsigned short v[8];
  int c = nt * 16 + (l & 15);
  #pragma unroll
  for (int j = 0; j < 8; ++j) {
    int k = kk * 32 + ((l >> 4) << 3) + j;
    float s = (k < 256) ? 1.f : -1.f;
    float val = (c < 128) ? s * w_e[k * 128 + c]
                          : -s * w_e[(k ^ 256) * 128 + (c - 128)];
    v[j] = f2bf(val);
  }
  ((uint4*)wcat)[bid * 64 + l] = *(const uint4*)v;
}

__global__ __launch_bounds__(NTH, 4) void kge_main3(
    const int* __restrict__ x,
    const float* __restrict__ e_emb, const float* __restrict__ r_emb,
    const float* __restrict__ d_frq, const float* __restrict__ d_phi, const float* __restrict__ d_amp,
    const float* __restrict__ m_frq, const float* __restrict__ m_phi, const float* __restrict__ m_amp,
    const float* __restrict__ w_rp,
    const unsigned short* __restrict__ tab, const unsigned short* __restrict__ wcat,
    float* __restrict__ out) {
  __shared__ __align__(16) unsigned short A[ERB][APAD];
  __shared__ __align__(16) unsigned short stb[ERB][256];
  __shared__ __align__(16) float p[ERB][256];
  __shared__ int meta[RPB][6];

  const int tid = threadIdx.x;
  const int base_row = blockIdx.x * RPB;
  const int w = tid >> 6, l = tid & 63;

  if (tid < RPB * 6) {
    int r = tid / 6, f = tid % 6;
    meta[r][f] = x[(size_t)(base_row + r) * XSTR + f];
  }
  __syncthreads();

  for (int i = tid; i < ERB * 128; i += NTH) {
    int er = i >> 7, k4 = i & 127;
    int e = (er & 1) ? meta[er >> 1][2] : meta[er >> 1][0];
    float4 v = ((const float4*)e_emb)[(size_t)e * 128 + k4];
    uint2 pk;
    pk.x = f2bf_u(v.x) | (f2bf_u(v.y) << 16);
    pk.y = f2bf_u(v.z) | (f2bf_u(v.w) << 16);
    *(uint2*)&A[er][k4 * 4] = pk;
  }
  for (int it = tid; it < ERB * 256; it += NTH) {
    int j = it & 255, er = it >> 8, r = er >> 1;
    int e = (er & 1) ? meta[r][2] : meta[r][0];
    float dv = (float)meta[r][3], mv = (float)meta[r][4];
    size_t b256 = (size_t)e * 256 + j, b128 = (size_t)e * 128 + (j & 127);
    float argd = fmaf(dv, d_frq[b256], d_phi[b256]);
    float argm = fmaf(mv, m_frq[b256], m_phi[b256]);
    float vd = (j < 128) ? d_amp[b128] * __cosf(argd) : d_amp[b128] * __sinf(argd);
    float vm = (j < 128) ? m_amp[b128] * __cosf(argm) : m_amp[b128] * __sinf(argm);
    stb[er][j] = f2bf(vd + vm);
  }

  float s0 = 0, s1 = 0, s2 = 0, s3 = 0, o0 = 0, o1 = 0, o2 = 0, o3 = 0;
  {
    const int wu  = __builtin_amdgcn_readfirstlane(w);
    const int rid = __builtin_amdgcn_readfirstlane(meta[wu][1]);
    const int*   cp = x + (size_t)(base_row + wu) * XSTR + 6;
    const float* wp = w_rp + (size_t)rid * 200;
    const uint2* tl = ((const uint2*)tab) + l;
    #pragma unroll 2
    for (int n = 0; n < 200; ++n) {
      float wv = wp[n];
      int cS = cp[n];
      int cO = cp[200 + n];
      uint2 qs = tl[(size_t)cS * 64];
      uint2 qo = tl[(size_t)cO * 64];
      s0 = fmaf(wv, bfLo(qs.x), s0); s1 = fmaf(wv, bfHi(qs.x), s1);
      s2 = fmaf(wv, bfLo(qs.y), s2); s3 = fmaf(wv, bfHi(qs.y), s3);
      o0 = fmaf(wv, bfLo(qo.x), o0); o1 = fmaf(wv, bfHi(qo.x), o1);
      o2 = fmaf(wv, bfLo(qo.y), o2); o3 = fmaf(wv, bfHi(qo.y), o3);
    }
  }
  __syncthreads();

  {
    float4v acc0 = {0, 0, 0, 0}, acc1 = {0, 0, 0, 0};
    const int nt0 = 2 * w, nt1 = 2 * w + 1;
    const short8v* bp = (const short8v*)wcat;
    const unsigned short* arow = &A[l & 15][(l >> 4) << 3];
    #pragma unroll 8
    for (int kk = 0; kk < 16; ++kk) {
      short8v a  = *(const short8v*)(arow + kk * 32);
      short8v b0 = bp[(kk * 16 + nt0) * 64 + l];
      short8v b1 = bp[(kk * 16 + nt1) * 64 + l];
      acc0 = __builtin_amdgcn_mfma_f32_16x16x32_bf16(a, b0, acc0, 0, 0, 0);
      acc1 = __builtin_amdgcn_mfma_f32_16x16x32_bf16(a, b1, acc1, 0, 0, 0);
    }
    int col = l & 15, rbase = (l >> 4) * 4;
    #pragma unroll
    for (int q = 0; q < 4; ++q) {
      p[rbase + q][nt0 * 16 + col] = acc0[q];
      p[rbase + q][nt1 * 16 + col] = acc1[q];
    }
  }
  __syncthreads();

  {
    int es = 2 * w, eo = 2 * w + 1;
    p[es][2 * l] += s0; p[es][2 * l + 1] += s1;
    p[es][128 + 2 * l] += s2; p[es][129 + 2 * l] += s3;
    p[eo][2 * l] += o0; p[eo][2 * l + 1] += o1;
    p[eo][128 + 2 * l] += o2; p[eo][129 + 2 * l] += o3;
  }
  __syncthreads();

  {
    int r = w;
    int rid = meta[r][1];
    float sabs = 0.f;
    #pragma unroll
    for (int u0 = 0; u0 < 384; u0 += 64) {
      int u = u0 + l;
      float ang = r_emb[(size_t)rid * 384 + u] * SCALE_ANG;
      float sr = __sinf(ang), cr = __cosf(ang);
      float res, ims, reo, imo;
      if (u < 256) {
        res = bf1(A[2 * r][u]);       ims = bf1(A[2 * r][256 + u]);
        reo = bf1(A[2 * r + 1][u]);   imo = bf1(A[2 * r + 1][256 + u]);
      } else {
        int uu = u - 256;
        res = bf1(stb[2 * r][uu]);     ims = bf1(stb[2 * r][128 + uu]);
        reo = bf1(stb[2 * r + 1][uu]); imo = bf1(stb[2 * r + 1][128 + uu]);
      }
      float rsc = res * cr - ims * sr - reo;
      float isc = res * sr + ims * cr - imo;
      sabs += sqrtf(rsc * rsc + isc * isc);
    }
    float srel = 0.f;
    #pragma unroll
    for (int u0 = 0; u0 < 128; u0 += 64) {
      int u = u0 + l;
      float dre = p[2 * r][u] - p[2 * r + 1][u];
      float dim = p[2 * r][128 + u] - p[2 * r + 1][128 + u];
      srel += sqrtf(dre * dre + dim * dim);
    }
    float tot = sabs + srel;
    #pragma unroll
    for (int off = 32; off > 0; off >>= 1) tot += __shfl_down(tot, off);
    if (l == 0) out[base_row + r] = GAMMA_C - tot;
  }
}

// ===========================================================================
extern "C" void kernel_launch(void* const* d_in, const int* in_sizes, int n_in,
                              void* d_out, int out_size, void* d_ws, size_t ws_size,
                              hipStream_t stream) {
  (void)in_sizes; (void)n_in; (void)out_size;
  const int*   x     = (const int*)d_in[0];
  const float* e_emb = (const float*)d_in[1];
  const float* r_emb = (const float*)d_in[2];
  const float* d_frq = (const float*)d_in[3];
  const float* d_phi = (const float*)d_in[4];
  const float* d_amp = (const float*)d_in[5];
  const float* m_frq = (const float*)d_in[6];
  const float* m_phi = (const float*)d_in[7];
  const float* m_amp = (const float*)d_in[8];
  const float* w_e   = (const float*)d_in[9];
  const float* w_rp  = (const float*)d_in[10];
  float* out = (float*)d_out;

  if (ws_size >= WS_FULL) {
    unsigned short* tf   = (unsigned short*)d_ws;
    unsigned short* wcat = (unsigned short*)((char*)d_ws + TF_BYTES);
    unsigned short* H    = (unsigned short*)((char*)d_ws + TF_BYTES + WCAT_BYTES);
    float*          P3   = (float*)((char*)d_ws + TF_BYTES + WCAT_BYTES + H_BYTES);
    kge_prep<<<dim3(NH_BLK + NT_BLK + NW_BLK), dim3(256), 0, stream>>>(
        x, w_rp, w_e, tf, wcat, H);
    kge_gemm<<<dim3(128, 2), dim3(512), 0, stream>>>(H, tf, P3);
    kge_main4<<<dim3(B_ROWS / RPB), dim3(NTH), 0, stream>>>(
        x, e_emb, r_emb, d_frq, d_phi, d_amp, m_frq, m_phi, m_amp,
        wcat, P3, out);
  } else if (ws_size >= WS_OLD) {
    unsigned short* tab  = (unsigned short*)d_ws;
    unsigned short* wcat = (unsigned short*)((char*)d_ws + OLDTAB_BYTES);
    kge_table_old<<<dim3(1000), dim3(128), 0, stream>>>(tab);
    kge_wcat_old<<<dim3(256), dim3(64), 0, stream>>>(w_e, wcat);
    kge_main3<<<dim3(B_ROWS / RPB), dim3(NTH), 0, stream>>>(
        x, e_emb, r_emb, d_frq, d_phi, d_amp, m_frq, m_phi, m_amp, w_rp,
        tab, wcat, out);
  }
}